// Round 11
// baseline (1780.336 us; speedup 1.0000x reference)
//
#include <hip/hip_runtime.h>
#include <hip/hip_bf16.h>
#include <math.h>

#define NODES 50000
#define NFEAT 64
#define DIM 128
#define HEADS 4
#define CHC 32
#define FFDIM 512
#define PHDIM 256
#define NEDGE 600000
#define LN_EPS 1e-5f
#define SLOPE 0.2f

typedef __attribute__((ext_vector_type(8))) short bf16x8;
typedef __attribute__((ext_vector_type(4))) float f32x4;
typedef __attribute__((ext_vector_type(4))) unsigned short us4;

__device__ __forceinline__ unsigned short f2bf(float f) {
    __hip_bfloat16 h = __float2bfloat16(f);
    return reinterpret_cast<unsigned short&>(h);
}
__device__ __forceinline__ float bf2f(unsigned short u) {
    return __uint_as_float(((unsigned int)u) << 16);
}

// ---------- helpers ----------
__device__ __forceinline__ void ln_stats128(float val, float* red, float& mean, float& rstd) {
    float s1 = val, s2 = val * val;
#pragma unroll
    for (int off = 32; off > 0; off >>= 1) {
        s1 += __shfl_xor(s1, off, 64);
        s2 += __shfl_xor(s2, off, 64);
    }
    int wv = threadIdx.x >> 6;
    if ((threadIdx.x & 63) == 0) { red[wv * 2] = s1; red[wv * 2 + 1] = s2; }
    __syncthreads();
    float t1 = red[0] + red[2];
    float t2 = red[1] + red[3];
    mean = t1 * (1.f / 128.f);
    float var = t2 * (1.f / 128.f) - mean * mean;
    rstd = rsqrtf(var + LN_EPS);
}

// ---------- CSR build ----------
__global__ void k_count(const int* __restrict__ dst, int* __restrict__ cnt) {
    int e = blockIdx.x * 256 + threadIdx.x;
    if (e < NEDGE) atomicAdd(&cnt[dst[e]], 1);
}

__global__ void k_scan(const int* __restrict__ deg, int* __restrict__ rp) {
    __shared__ int sh[1024];
    int t = threadIdx.x;
    const int per = (NODES + 1023) / 1024;
    int beg = t * per;
    int end = beg + per; if (end > NODES) end = NODES; if (beg > NODES) beg = NODES;
    int s = 0;
    for (int i = beg; i < end; i++) s += deg[i];
    sh[t] = s;
    __syncthreads();
    for (int off = 1; off < 1024; off <<= 1) {
        int v = (t >= off) ? sh[t - off] : 0;
        __syncthreads();
        sh[t] += v;
        __syncthreads();
    }
    int run = sh[t] - s;  // exclusive prefix
    for (int i = beg; i < end; i++) { rp[i] = run; run += deg[i]; }
    if (t == 1023) rp[NODES] = sh[1023];
}

__global__ void k_fill(const int* __restrict__ ei, const int* __restrict__ rp,
                       int* __restrict__ cnt, int* __restrict__ ci) {
    int e = blockIdx.x * 256 + threadIdx.x;
    if (e < NEDGE) {
        int s = ei[e], d = ei[NEDGE + e];
        int pos = atomicAdd(&cnt[d], 1);
        ci[rp[d] + pos] = s;
    }
}

// ---------- weight transpose + split-bf16 convert: hi/lo of in[k*NR+n] ----------
template <int KI, int NR>
__global__ void k_wcvt2(const float* __restrict__ in, unsigned short* __restrict__ oh,
                        unsigned short* __restrict__ ol) {
    int tid = blockIdx.x * 256 + threadIdx.x;  // KI*NR total
    int n = tid / KI, k = tid % KI;
    float w = in[k * NR + n];
    unsigned short h = f2bf(w);
    oh[tid] = h;
    ol[tid] = f2bf(w - bf2f(h));
}

// ---------- preprocessing: x = LN(relu(x0 @ Wp + bp)) ----------
__global__ void k_preprocess(const float* __restrict__ x0, const float* __restrict__ Wp,
                             const float* __restrict__ bp, const float* __restrict__ g,
                             const float* __restrict__ b, float* __restrict__ xout) {
    __shared__ float xr[NFEAT];
    __shared__ float red[4];
    int n = blockIdx.x;
    int j = threadIdx.x;
    if (j < NFEAT) xr[j] = x0[n * NFEAT + j];
    __syncthreads();
    float acc = bp[j];
#pragma unroll
    for (int k = 0; k < NFEAT; k++) acc += xr[k] * Wp[k * DIM + j];
    acc = fmaxf(acc, 0.f);
    float mean, rstd;
    ln_stats128(acc, red, mean, rstd);
    xout[n * DIM + j] = (acc - mean) * rstd * g[j] + b[j];
}

#define XS_STRIDE 136   // 128 + 8 bf16 pad (272 B rows, 16B-aligned)
#define HID_STRIDE 520  // 512 + 8 bf16 pad (1040 B rows)
#define FB_STRIDE 132   // fp32 resid buffer stride
#define MFMA_BF16 __builtin_amdgcn_mfma_f32_16x16x32_bf16

// ---------- split-bf16 MFMA: hg = x @ W ; fused attention logits ----------
// NO __launch_bounds__ on split-bf16 MFMA kernels (session finding).
__global__ void k_xw_mfma(const float* __restrict__ x,
                          const unsigned short* __restrict__ Wh,
                          const unsigned short* __restrict__ Wl,
                          const float* __restrict__ a_s, const float* __restrict__ a_d,
                          float* __restrict__ hg, float* __restrict__ als,
                          float* __restrict__ ald) {
    __shared__ __align__(16) unsigned short xsh[32 * XS_STRIDE];
    __shared__ __align__(16) unsigned short xsl[32 * XS_STRIDE];
    int t = threadIdx.x;
    int n0 = blockIdx.x * 32;

#pragma unroll
    for (int jj = 0; jj < 4; jj++) {
        int v = t + jj * 256;  // 1024 float4s = 32 rows x 32 float4
        int m = v >> 5, c4 = (v & 31) * 4;
        int node = n0 + m;
        float4 f;
        if (node < NODES) f = *(const float4*)(x + (size_t)node * DIM + c4);
        else { f.x = f.y = f.z = f.w = 0.f; }
        us4 uh = {f2bf(f.x), f2bf(f.y), f2bf(f.z), f2bf(f.w)};
        us4 ul = {f2bf(f.x - bf2f(uh.x)), f2bf(f.y - bf2f(uh.y)),
                  f2bf(f.z - bf2f(uh.z)), f2bf(f.w - bf2f(uh.w))};
        *(us4*)(xsh + m * XS_STRIDE + c4) = uh;
        *(us4*)(xsl + m * XS_STRIDE + c4) = ul;
    }
    __syncthreads();

    int wv = t >> 6, l = t & 63, lr = l & 15, lk = l >> 4;

    f32x4 acc[2][2];
#pragma unroll
    for (int mf = 0; mf < 2; mf++)
#pragma unroll
        for (int nf = 0; nf < 2; nf++) acc[mf][nf] = (f32x4){0.f, 0.f, 0.f, 0.f};
#pragma unroll
    for (int kk = 0; kk < 4; kk++) {
        int c = kk * 32 + lk * 8;
        bf16x8 a0h = *(const bf16x8*)(xsh + lr * XS_STRIDE + c);
        bf16x8 a0l = *(const bf16x8*)(xsl + lr * XS_STRIDE + c);
        bf16x8 a1h = *(const bf16x8*)(xsh + (16 + lr) * XS_STRIDE + c);
        bf16x8 a1l = *(const bf16x8*)(xsl + (16 + lr) * XS_STRIDE + c);
#pragma unroll
        for (int nf = 0; nf < 2; nf++) {
            int n = wv * 32 + nf * 16 + lr;
            bf16x8 bh = *(const bf16x8*)(Wh + (size_t)n * DIM + c);
            bf16x8 bl = *(const bf16x8*)(Wl + (size_t)n * DIM + c);
            acc[0][nf] = MFMA_BF16(a0h, bh, acc[0][nf], 0, 0, 0);
            acc[0][nf] = MFMA_BF16(a0l, bh, acc[0][nf], 0, 0, 0);
            acc[0][nf] = MFMA_BF16(a0h, bl, acc[0][nf], 0, 0, 0);
            acc[1][nf] = MFMA_BF16(a1h, bh, acc[1][nf], 0, 0, 0);
            acc[1][nf] = MFMA_BF16(a1l, bh, acc[1][nf], 0, 0, 0);
            acc[1][nf] = MFMA_BF16(a1h, bl, acc[1][nf], 0, 0, 0);
        }
    }

    float as0 = a_s[wv * 32 + lr], as1 = a_s[wv * 32 + 16 + lr];
    float ad0 = a_d[wv * 32 + lr], ad1 = a_d[wv * 32 + 16 + lr];
#pragma unroll
    for (int mf = 0; mf < 2; mf++) {
#pragma unroll
        for (int r = 0; r < 4; r++) {
            int m = mf * 16 + lk * 4 + r;
            int node = n0 + m;
            float v0 = acc[mf][0][r], v1 = acc[mf][1][r];
            if (node < NODES) {
                hg[(size_t)node * DIM + wv * 32 + lr] = v0;
                hg[(size_t)node * DIM + wv * 32 + 16 + lr] = v1;
            }
            float ps = v0 * as0 + v1 * as1;
            float pd = v0 * ad0 + v1 * ad1;
#pragma unroll
            for (int off = 8; off > 0; off >>= 1) {
                ps += __shfl_xor(ps, off, 64);
                pd += __shfl_xor(pd, off, 64);
            }
            if (lr == 0 && node < NODES) {
                als[node * HEADS + wv] = ps;
                ald[node * HEADS + wv] = pd;
            }
        }
    }
}

// ---------- GAT aggregate + bias + residual + LN (4-deep edge pipeline) ----------
__global__ void k_agg(const float* __restrict__ x, const float* __restrict__ hg,
                      const float* __restrict__ als, const float* __restrict__ ald,
                      const int* __restrict__ rp, const int* __restrict__ ci,
                      const float* __restrict__ bias, const float* __restrict__ g,
                      const float* __restrict__ b, float* __restrict__ y) {
    __shared__ float red[4];
    int n = blockIdx.x, j = threadIdx.x, head = j >> 5;
    float aldn = ald[n * HEADS + head];
    float a0 = als[n * HEADS + head] + aldn;
    a0 = (a0 > 0.f) ? a0 : SLOPE * a0;
    float ex = __expf(a0);
    float den = ex;
    float acc = ex * hg[(size_t)n * DIM + j];
    int beg = rp[n], end = rp[n + 1];
    int e = beg;
    // 4-deep pipeline: batch index loads -> logit loads -> exps -> 4 independent row gathers
    for (; e + 4 <= end; e += 4) {
        int s0 = ci[e], s1 = ci[e + 1], s2 = ci[e + 2], s3 = ci[e + 3];
        float av0 = als[s0 * HEADS + head] + aldn;
        float av1 = als[s1 * HEADS + head] + aldn;
        float av2 = als[s2 * HEADS + head] + aldn;
        float av3 = als[s3 * HEADS + head] + aldn;
        av0 = (av0 > 0.f) ? av0 : SLOPE * av0;
        av1 = (av1 > 0.f) ? av1 : SLOPE * av1;
        av2 = (av2 > 0.f) ? av2 : SLOPE * av2;
        av3 = (av3 > 0.f) ? av3 : SLOPE * av3;
        float e0 = __expf(av0), e1 = __expf(av1), e2 = __expf(av2), e3 = __expf(av3);
        float h0 = hg[(size_t)s0 * DIM + j];
        float h1 = hg[(size_t)s1 * DIM + j];
        float h2 = hg[(size_t)s2 * DIM + j];
        float h3 = hg[(size_t)s3 * DIM + j];
        den += (e0 + e1) + (e2 + e3);
        acc += e0 * h0 + e1 * h1 + e2 * h2 + e3 * h3;
    }
    for (; e < end; e++) {
        int s = ci[e];
        float av = als[s * HEADS + head] + aldn;
        av = (av > 0.f) ? av : SLOPE * av;
        float e2 = __expf(av);
        den += e2;
        acc += e2 * hg[(size_t)s * DIM + j];
    }
    float val = x[(size_t)n * DIM + j] + acc / den + bias[j];
    float mean, rstd;
    ln_stats128(val, red, mean, rstd);
    y[(size_t)n * DIM + j] = (val - mean) * rstd * g[j] + b[j];
}

// ---------- split-bf16 MFMA fused FFN: x = LN(y + relu(y@W1+b1)@W2+b2) ----------
// Re-waved to 1024 threads (16 waves); TM=32, 84KB LDS (1 block/CU — session
// law: this kernel is only correct at 1 block/CU; do NOT shrink LDS or add
// launch_bounds). Per-element MFMA chains identical to the passing R8/R10:
// wave wv owns m-half (wv&1) and column group (wv>>1).
#define TM 32

__global__ void k_ffn_mfma(
    const float* __restrict__ yin,
    const unsigned short* __restrict__ W1h, const unsigned short* __restrict__ W1l,
    const float* __restrict__ b1,
    const unsigned short* __restrict__ W2h, const unsigned short* __restrict__ W2l,
    const float* __restrict__ b2, const float* __restrict__ g,
    const float* __restrict__ b, float* __restrict__ xout) {
    __shared__ __align__(16) unsigned char smem[(2 * TM * XS_STRIDE + 2 * TM * HID_STRIDE) * 2];
    unsigned short* xsh = (unsigned short*)smem;        // [32][136] bf16 hi
    unsigned short* xsl = xsh + TM * XS_STRIDE;         // [32][136] bf16 lo
    unsigned short* hidh = xsl + TM * XS_STRIDE;        // [32][520] bf16 hi
    unsigned short* hidl = hidh + TM * HID_STRIDE;      // [32][520] bf16 lo
    float* fbuf = (float*)hidh;                         // reuse: [32][132] fp32

    int t = threadIdx.x;  // 1024
    int n0 = blockIdx.x * TM;

    // stage yin tile -> split bf16 LDS (1024 float4s = 32 rows x 32 float4)
    {
        int m = t >> 5, c4 = (t & 31) * 4;
        int node = n0 + m;
        float4 f;
        if (node < NODES) f = *(const float4*)(yin + (size_t)node * DIM + c4);
        else { f.x = f.y = f.z = f.w = 0.f; }
        us4 uh = {f2bf(f.x), f2bf(f.y), f2bf(f.z), f2bf(f.w)};
        us4 ul = {f2bf(f.x - bf2f(uh.x)), f2bf(f.y - bf2f(uh.y)),
                  f2bf(f.z - bf2f(uh.z)), f2bf(f.w - bf2f(uh.w))};
        *(us4*)(xsh + m * XS_STRIDE + c4) = uh;
        *(us4*)(xsl + m * XS_STRIDE + c4) = ul;
    }
    __syncthreads();

    int wv = t >> 6, l = t & 63, lr = l & 15, lk = l >> 4;  // wv in [0,16)
    int mh = (wv & 1) * 16;   // m-half base row
    int cg = wv >> 1;         // column group [0,8)

    // phase 1: hid = relu(xs @ W1 + b1); wave owns rows [mh,mh+16) x cols [cg*64, cg*64+64)
    {
        f32x4 acc[4];
#pragma unroll
        for (int nf = 0; nf < 4; nf++) acc[nf] = (f32x4){0.f, 0.f, 0.f, 0.f};
#pragma unroll
        for (int kk = 0; kk < 4; kk++) {
            int c = kk * 32 + lk * 8;
            bf16x8 ah = *(const bf16x8*)(xsh + (mh + lr) * XS_STRIDE + c);
            bf16x8 al = *(const bf16x8*)(xsl + (mh + lr) * XS_STRIDE + c);
#pragma unroll
            for (int nf = 0; nf < 4; nf++) {
                int n = cg * 64 + nf * 16 + lr;
                bf16x8 bh = *(const bf16x8*)(W1h + (size_t)n * DIM + c);
                bf16x8 bl = *(const bf16x8*)(W1l + (size_t)n * DIM + c);
                acc[nf] = MFMA_BF16(ah, bh, acc[nf], 0, 0, 0);
                acc[nf] = MFMA_BF16(al, bh, acc[nf], 0, 0, 0);
                acc[nf] = MFMA_BF16(ah, bl, acc[nf], 0, 0, 0);
            }
        }
#pragma unroll
        for (int nf = 0; nf < 4; nf++) {
            int n = cg * 64 + nf * 16 + lr;
            float bias = b1[n];
#pragma unroll
            for (int r = 0; r < 4; r++) {
                int m = mh + lk * 4 + r;
                float val = fmaxf(acc[nf][r] + bias, 0.f);
                unsigned short h = f2bf(val);
                hidh[m * HID_STRIDE + n] = h;
                hidl[m * HID_STRIDE + n] = f2bf(val - bf2f(h));
            }
        }
    }
    __syncthreads();

    // phase 2: f = hid @ W2; wave owns rows [mh,mh+16) x cols [cg*16, cg*16+16)
    f32x4 acc2 = (f32x4){0.f, 0.f, 0.f, 0.f};
#pragma unroll
    for (int kk = 0; kk < 16; kk++) {
        int c = kk * 32 + lk * 8;
        bf16x8 ah = *(const bf16x8*)(hidh + (mh + lr) * HID_STRIDE + c);
        bf16x8 al = *(const bf16x8*)(hidl + (mh + lr) * HID_STRIDE + c);
        int n = cg * 16 + lr;
        bf16x8 bh = *(const bf16x8*)(W2h + (size_t)n * FFDIM + c);
        bf16x8 bl = *(const bf16x8*)(W2l + (size_t)n * FFDIM + c);
        acc2 = MFMA_BF16(ah, bh, acc2, 0, 0, 0);
        acc2 = MFMA_BF16(al, bh, acc2, 0, 0, 0);
        acc2 = MFMA_BF16(ah, bl, acc2, 0, 0, 0);
    }
    __syncthreads();  // all hid reads done before fbuf overwrite

    // residual + bias into fp32 LDS
    {
        int n = cg * 16 + lr;
        float bias = b2[n];
#pragma unroll
        for (int r = 0; r < 4; r++) {
            int m = mh + lk * 4 + r;
            int node = n0 + m;
            float yv = (node < NODES) ? yin[(size_t)node * DIM + n] : 0.f;
            fbuf[m * FB_STRIDE + n] = acc2[r] + bias + yv;
        }
    }
    __syncthreads();

    // LN: 32 threads per row, 4 cols each (1024 threads / 32 rows)
    {
        int row = t >> 5, l32 = t & 31;
        float4 vv = *(float4*)(fbuf + row * FB_STRIDE + l32 * 4);
        float s1 = vv.x + vv.y + vv.z + vv.w;
        float s2 = vv.x * vv.x + vv.y * vv.y + vv.z * vv.z + vv.w * vv.w;
#pragma unroll
        for (int off = 16; off > 0; off >>= 1) {
            s1 += __shfl_xor(s1, off, 64);
            s2 += __shfl_xor(s2, off, 64);
        }
        float mean = s1 * (1.f / 128.f);
        float var = s2 * (1.f / 128.f) - mean * mean;
        float rstd = rsqrtf(var + LN_EPS);
        int node = n0 + row;
        if (node < NODES) {
            int c = l32 * 4;
            float4 gv = *(const float4*)(g + c);
            float4 bv = *(const float4*)(b + c);
            float4 o;
            o.x = (vv.x - mean) * rstd * gv.x + bv.x;
            o.y = (vv.y - mean) * rstd * gv.y + bv.y;
            o.z = (vv.z - mean) * rstd * gv.z + bv.z;
            o.w = (vv.w - mean) * rstd * gv.w + bv.w;
            *(float4*)(xout + (size_t)node * DIM + c) = o;
        }
    }
}

// ---------- predictor precompute: P = h@We1_top + be1, Q = h@We1_bot (bf16) ----------
#define TF 16
__global__ void k_pq(const float* __restrict__ h, const float* __restrict__ We1,
                     const float* __restrict__ be1, __hip_bfloat16* __restrict__ P,
                     __hip_bfloat16* __restrict__ Q) {
    __shared__ float xs[TF][DIM];
    int n0 = blockIdx.x * TF;
    int t = threadIdx.x;  // 256
    for (int i = t; i < TF * DIM; i += 256) {
        int e = i >> 7, k = i & 127;
        xs[e][k] = h[(size_t)(n0 + e) * DIM + k];
    }
    __syncthreads();
    float accP[TF], accQ[TF];
#pragma unroll
    for (int e = 0; e < TF; e++) { accP[e] = be1[t]; accQ[e] = 0.f; }
    for (int k = 0; k < DIM; k++) {
        float wp = We1[k * PHDIM + t];
        float wq = We1[(DIM + k) * PHDIM + t];
#pragma unroll
        for (int e = 0; e < TF; e++) {
            float xv = xs[e][k];
            accP[e] += xv * wp;
            accQ[e] += xv * wq;
        }
    }
#pragma unroll
    for (int e = 0; e < TF; e++) {
        P[(size_t)(n0 + e) * PHDIM + t] = __float2bfloat16(accP[e]);
        Q[(size_t)(n0 + e) * PHDIM + t] = __float2bfloat16(accQ[e]);
    }
}

// ---------- edge predictor: flow = relu(relu(P[s]+Q[d]) . We2 + be2) ----------
__global__ void k_edge(const int* __restrict__ ei, const __hip_bfloat16* __restrict__ P,
                       const __hip_bfloat16* __restrict__ Q, const float* __restrict__ We2,
                       const float* __restrict__ be2, float* __restrict__ out) {
    int lane = threadIdx.x & 63;
    int wv = threadIdx.x >> 6;
    int e = blockIdx.x * 4 + wv;
    if (e >= NEDGE) return;
    float4 w2 = ((const float4*)We2)[lane];
    int s = ei[e], d = ei[NEDGE + e];
    uint2 pu = ((const uint2*)P)[(size_t)s * 64 + lane];
    uint2 qu = ((const uint2*)Q)[(size_t)d * 64 + lane];
    float p0 = __uint_as_float(pu.x << 16);
    float p1 = __uint_as_float(pu.x & 0xffff0000u);
    float p2 = __uint_as_float(pu.y << 16);
    float p3 = __uint_as_float(pu.y & 0xffff0000u);
    float q0 = __uint_as_float(qu.x << 16);
    float q1 = __uint_as_float(qu.x & 0xffff0000u);
    float q2 = __uint_as_float(qu.y << 16);
    float q3 = __uint_as_float(qu.y & 0xffff0000u);
    float acc = fmaxf(p0 + q0, 0.f) * w2.x + fmaxf(p1 + q1, 0.f) * w2.y +
                fmaxf(p2 + q2, 0.f) * w2.z + fmaxf(p3 + q3, 0.f) * w2.w;
#pragma unroll
    for (int off = 32; off > 0; off >>= 1) acc += __shfl_xor(acc, off, 64);
    if (lane == 0) out[e] = fmaxf(acc + be2[0], 0.f);
}

extern "C" void kernel_launch(void* const* d_in, const int* in_sizes, int n_in,
                              void* d_out, int out_size, void* d_ws, size_t ws_size,
                              hipStream_t stream) {
    const float* x0   = (const float*)d_in[0];
    const int*   eiR  = (const int*)d_in[1];
    const int*   eiV  = (const int*)d_in[2];
    const float* Wp   = (const float*)d_in[3];
    const float* bp   = (const float*)d_in[4];
    const float* lnpg = (const float*)d_in[5];
    const float* lnpb = (const float*)d_in[6];
    const float* vW   = (const float*)d_in[7];
    const float* v_as = (const float*)d_in[8];
    const float* v_ad = (const float*)d_in[9];
    const float* v_b  = (const float*)d_in[10];
    const float* vW1  = (const float*)d_in[11];
    const float* vb1  = (const float*)d_in[12];
    const float* vW2  = (const float*)d_in[13];
    const float* vb2  = (const float*)d_in[14];
    const float* vln1g = (const float*)d_in[15];
    const float* vln1b = (const float*)d_in[16];
    const float* vln2g = (const float*)d_in[17];
    const float* vln2b = (const float*)d_in[18];
    const float* rW   = (const float*)d_in[19];
    const float* r_as = (const float*)d_in[20];
    const float* r_ad = (const float*)d_in[21];
    const float* r_b  = (const float*)d_in[22];
    const float* rW1  = (const float*)d_in[23];
    const float* rb1  = (const float*)d_in[24];
    const float* rW2  = (const float*)d_in[25];
    const float* rb2  = (const float*)d_in[26];
    const float* rln1g = (const float*)d_in[27];
    const float* rln1b = (const float*)d_in[28];
    const float* rln2g = (const float*)d_in[29];
    const float* rln2b = (const float*)d_in[30];
    const float* We1  = (const float*)d_in[31];
    const float* be1  = (const float*)d_in[32];
    const float* We2  = (const float*)d_in[33];
    const float* be2  = (const float*)d_in[34];
    float* out = (float*)d_out;

    // workspace layout (16B-aligned segments first)
    float* X   = (float*)d_ws;                       // N*DIM
    float* Y   = X + (size_t)NODES * DIM;            // N*DIM
    float* HG  = Y + (size_t)NODES * DIM;            // N*DIM
    float* ALS = HG + (size_t)NODES * DIM;           // N*HEADS
    float* ALD = ALS + (size_t)NODES * HEADS;        // N*HEADS
    __hip_bfloat16* Pb = (__hip_bfloat16*)(ALD + (size_t)NODES * HEADS);  // N*PHDIM bf16
    __hip_bfloat16* Qb = Pb + (size_t)NODES * PHDIM;                      // N*PHDIM bf16
    // per layer: W1h, W1l, W2h, W2l each 65536 bf16
    unsigned short* WT = (unsigned short*)(Qb + (size_t)NODES * PHDIM);   // 4*4*65536 bf16
    // per layer: GAT W hi/lo each 16384 bf16
    unsigned short* WXT = WT + (size_t)4 * 4 * 65536;                     // 4*2*16384 bf16
    int* rpV = (int*)(WXT + (size_t)4 * 2 * 16384);  // N+1
    int* ciV = rpV + (NODES + 1);                    // E
    int* rpR = ciV + NEDGE;                          // N+1
    int* ciR = rpR + (NODES + 1);                    // E
    int* cnt = ciR + NEDGE;                          // N

    const int EB = (NEDGE + 255) / 256;

    // CSR for virtual graph
    hipMemsetAsync(cnt, 0, sizeof(int) * NODES, stream);
    k_count<<<EB, 256, 0, stream>>>(eiV + NEDGE, cnt);
    k_scan<<<1, 1024, 0, stream>>>(cnt, rpV);
    hipMemsetAsync(cnt, 0, sizeof(int) * NODES, stream);
    k_fill<<<EB, 256, 0, stream>>>(eiV, rpV, cnt, ciV);
    // CSR for real graph
    hipMemsetAsync(cnt, 0, sizeof(int) * NODES, stream);
    k_count<<<EB, 256, 0, stream>>>(eiR + NEDGE, cnt);
    k_scan<<<1, 1024, 0, stream>>>(cnt, rpR);
    hipMemsetAsync(cnt, 0, sizeof(int) * NODES, stream);
    k_fill<<<EB, 256, 0, stream>>>(eiR, rpR, cnt, ciR);

    // weight transpose + split-bf16 (once per launch; L2-resident afterwards)
    for (int l = 0; l < 4; l++) {
        bool virt = (l < 2);
        int i = virt ? l : (l - 2);
        const float* W1 = (virt ? vW1 : rW1) + (size_t)i * DIM * FFDIM;
        const float* W2 = (virt ? vW2 : rW2) + (size_t)i * FFDIM * DIM;
        const float* W  = (virt ? vW : rW) + (size_t)i * DIM * DIM;
        unsigned short* base = WT + (size_t)l * 262144;
        k_wcvt2<DIM, FFDIM><<<256, 256, 0, stream>>>(W1, base, base + 65536);            // W1T[512][128] hi/lo
        k_wcvt2<FFDIM, DIM><<<256, 256, 0, stream>>>(W2, base + 131072, base + 196608);  // W2T[128][512] hi/lo
        unsigned short* bx = WXT + (size_t)l * 32768;
        k_wcvt2<DIM, DIM><<<64, 256, 0, stream>>>(W, bx, bx + 16384);                    // WT[128][128] hi/lo
    }

    // preprocessing
    k_preprocess<<<NODES, 128, 0, stream>>>(x0, Wp, bp, lnpg, lnpb, X);

    // 4 encoder layers: 2 virtual, 2 real
    for (int l = 0; l < 4; l++) {
        bool virt = (l < 2);
        int i = virt ? l : (l - 2);
        const float* As = (virt ? v_as : r_as) + (size_t)i * HEADS * CHC;
        const float* Ad = (virt ? v_ad : r_ad) + (size_t)i * HEADS * CHC;
        const float* Bb = (virt ? v_b : r_b) + (size_t)i * DIM;
        const float* B1 = (virt ? vb1 : rb1) + (size_t)i * FFDIM;
        const float* B2 = (virt ? vb2 : rb2) + (size_t)i * DIM;
        const float* G1 = (virt ? vln1g : rln1g) + (size_t)i * DIM;
        const float* B1n = (virt ? vln1b : rln1b) + (size_t)i * DIM;
        const float* G2 = (virt ? vln2g : rln2g) + (size_t)i * DIM;
        const float* B2n = (virt ? vln2b : rln2b) + (size_t)i * DIM;
        const int* rp = virt ? rpV : rpR;
        const int* ci = virt ? ciV : ciR;

        unsigned short* bx = WXT + (size_t)l * 32768;
        k_xw_mfma<<<(NODES + 31) / 32, 256, 0, stream>>>(X, bx, bx + 16384, As, Ad, HG, ALS, ALD);
        k_agg<<<NODES, 128, 0, stream>>>(X, HG, ALS, ALD, rp, ci, Bb, G1, B1n, Y);
        unsigned short* base = WT + (size_t)l * 262144;
        k_ffn_mfma<<<(NODES + TM - 1) / TM, 1024, 0, stream>>>(
            Y, base, base + 65536, B1, base + 131072, base + 196608, B2, G2, B2n, X);
    }

    // edge predictor
    k_pq<<<NODES / TF, 256, 0, stream>>>(X, We1, be1, Pb, Qb);
    k_edge<<<(NEDGE + 3) / 4, 256, 0, stream>>>(eiR, Pb, Qb, We2, be2, out);
}

// Round 12
// 1394.940 us; speedup vs baseline: 1.2763x; 1.2763x over previous
//
#include <hip/hip_runtime.h>
#include <hip/hip_bf16.h>
#include <math.h>

#define NODES 50000
#define NFEAT 64
#define DIM 128
#define HEADS 4
#define CHC 32
#define FFDIM 512
#define PHDIM 256
#define NEDGE 600000
#define LN_EPS 1e-5f
#define SLOPE 0.2f

typedef __attribute__((ext_vector_type(8))) short bf16x8;
typedef __attribute__((ext_vector_type(4))) float f32x4;
typedef __attribute__((ext_vector_type(4))) unsigned short us4;

__device__ __forceinline__ unsigned short f2bf(float f) {
    __hip_bfloat16 h = __float2bfloat16(f);
    return reinterpret_cast<unsigned short&>(h);
}
__device__ __forceinline__ float bf2f(unsigned short u) {
    return __uint_as_float(((unsigned int)u) << 16);
}

// ---------- helpers ----------
__device__ __forceinline__ void ln_stats128(float val, float* red, float& mean, float& rstd) {
    float s1 = val, s2 = val * val;
#pragma unroll
    for (int off = 32; off > 0; off >>= 1) {
        s1 += __shfl_xor(s1, off, 64);
        s2 += __shfl_xor(s2, off, 64);
    }
    int wv = threadIdx.x >> 6;
    if ((threadIdx.x & 63) == 0) { red[wv * 2] = s1; red[wv * 2 + 1] = s2; }
    __syncthreads();
    float t1 = red[0] + red[2];
    float t2 = red[1] + red[3];
    mean = t1 * (1.f / 128.f);
    float var = t2 * (1.f / 128.f) - mean * mean;
    rstd = rsqrtf(var + LN_EPS);
}

// ---------- CSR build ----------
__global__ void k_count(const int* __restrict__ dst, int* __restrict__ cnt) {
    int e = blockIdx.x * 256 + threadIdx.x;
    if (e < NEDGE) atomicAdd(&cnt[dst[e]], 1);
}

__global__ void k_scan(const int* __restrict__ deg, int* __restrict__ rp) {
    __shared__ int sh[1024];
    int t = threadIdx.x;
    const int per = (NODES + 1023) / 1024;
    int beg = t * per;
    int end = beg + per; if (end > NODES) end = NODES; if (beg > NODES) beg = NODES;
    int s = 0;
    for (int i = beg; i < end; i++) s += deg[i];
    sh[t] = s;
    __syncthreads();
    for (int off = 1; off < 1024; off <<= 1) {
        int v = (t >= off) ? sh[t - off] : 0;
        __syncthreads();
        sh[t] += v;
        __syncthreads();
    }
    int run = sh[t] - s;  // exclusive prefix
    for (int i = beg; i < end; i++) { rp[i] = run; run += deg[i]; }
    if (t == 1023) rp[NODES] = sh[1023];
}

__global__ void k_fill(const int* __restrict__ ei, const int* __restrict__ rp,
                       int* __restrict__ cnt, int* __restrict__ ci) {
    int e = blockIdx.x * 256 + threadIdx.x;
    if (e < NEDGE) {
        int s = ei[e], d = ei[NEDGE + e];
        int pos = atomicAdd(&cnt[d], 1);
        ci[rp[d] + pos] = s;
    }
}

// ---------- weight transpose + split-bf16 convert: hi/lo of in[k*NR+n] ----------
template <int KI, int NR>
__global__ void k_wcvt2(const float* __restrict__ in, unsigned short* __restrict__ oh,
                        unsigned short* __restrict__ ol) {
    int tid = blockIdx.x * 256 + threadIdx.x;  // KI*NR total
    int n = tid / KI, k = tid % KI;
    float w = in[k * NR + n];
    unsigned short h = f2bf(w);
    oh[tid] = h;
    ol[tid] = f2bf(w - bf2f(h));
}

// We1 [2*DIM][PHDIM] -> combined [512][128] hi/lo: rows 0-255 = P cols (We1 top),
// rows 256-511 = Q cols (We1 bottom)
__global__ void k_wcvt_pq(const float* __restrict__ We1, unsigned short* __restrict__ oh,
                          unsigned short* __restrict__ ol) {
    int tid = blockIdx.x * 256 + threadIdx.x;  // 512*128
    int n = tid >> 7, k = tid & 127;
    float w = (n < PHDIM) ? We1[k * PHDIM + n] : We1[(DIM + k) * PHDIM + (n - PHDIM)];
    unsigned short h = f2bf(w);
    oh[tid] = h;
    ol[tid] = f2bf(w - bf2f(h));
}

// ---------- preprocessing: x = LN(relu(x0 @ Wp + bp)) ----------
__global__ void k_preprocess(const float* __restrict__ x0, const float* __restrict__ Wp,
                             const float* __restrict__ bp, const float* __restrict__ g,
                             const float* __restrict__ b, float* __restrict__ xout) {
    __shared__ float xr[NFEAT];
    __shared__ float red[4];
    int n = blockIdx.x;
    int j = threadIdx.x;
    if (j < NFEAT) xr[j] = x0[n * NFEAT + j];
    __syncthreads();
    float acc = bp[j];
#pragma unroll
    for (int k = 0; k < NFEAT; k++) acc += xr[k] * Wp[k * DIM + j];
    acc = fmaxf(acc, 0.f);
    float mean, rstd;
    ln_stats128(acc, red, mean, rstd);
    xout[n * DIM + j] = (acc - mean) * rstd * g[j] + b[j];
}

#define XS_STRIDE 136   // 128 + 8 bf16 pad (272 B rows, 16B-aligned)
#define HID_STRIDE 520  // 512 + 8 bf16 pad (1040 B rows)
#define FB_STRIDE 132   // fp32 resid buffer stride
#define MFMA_BF16 __builtin_amdgcn_mfma_f32_16x16x32_bf16

// ---------- split-bf16 MFMA: hg = x @ W ; fused attention logits ----------
// NO __launch_bounds__ on split-bf16 MFMA kernels (session finding).
__global__ void k_xw_mfma(const float* __restrict__ x,
                          const unsigned short* __restrict__ Wh,
                          const unsigned short* __restrict__ Wl,
                          const float* __restrict__ a_s, const float* __restrict__ a_d,
                          float* __restrict__ hg, float* __restrict__ als,
                          float* __restrict__ ald) {
    __shared__ __align__(16) unsigned short xsh[32 * XS_STRIDE];
    __shared__ __align__(16) unsigned short xsl[32 * XS_STRIDE];
    int t = threadIdx.x;
    int n0 = blockIdx.x * 32;

#pragma unroll
    for (int jj = 0; jj < 4; jj++) {
        int v = t + jj * 256;  // 1024 float4s = 32 rows x 32 float4
        int m = v >> 5, c4 = (v & 31) * 4;
        int node = n0 + m;
        float4 f;
        if (node < NODES) f = *(const float4*)(x + (size_t)node * DIM + c4);
        else { f.x = f.y = f.z = f.w = 0.f; }
        us4 uh = {f2bf(f.x), f2bf(f.y), f2bf(f.z), f2bf(f.w)};
        us4 ul = {f2bf(f.x - bf2f(uh.x)), f2bf(f.y - bf2f(uh.y)),
                  f2bf(f.z - bf2f(uh.z)), f2bf(f.w - bf2f(uh.w))};
        *(us4*)(xsh + m * XS_STRIDE + c4) = uh;
        *(us4*)(xsl + m * XS_STRIDE + c4) = ul;
    }
    __syncthreads();

    int wv = t >> 6, l = t & 63, lr = l & 15, lk = l >> 4;

    f32x4 acc[2][2];
#pragma unroll
    for (int mf = 0; mf < 2; mf++)
#pragma unroll
        for (int nf = 0; nf < 2; nf++) acc[mf][nf] = (f32x4){0.f, 0.f, 0.f, 0.f};
#pragma unroll
    for (int kk = 0; kk < 4; kk++) {
        int c = kk * 32 + lk * 8;
        bf16x8 a0h = *(const bf16x8*)(xsh + lr * XS_STRIDE + c);
        bf16x8 a0l = *(const bf16x8*)(xsl + lr * XS_STRIDE + c);
        bf16x8 a1h = *(const bf16x8*)(xsh + (16 + lr) * XS_STRIDE + c);
        bf16x8 a1l = *(const bf16x8*)(xsl + (16 + lr) * XS_STRIDE + c);
#pragma unroll
        for (int nf = 0; nf < 2; nf++) {
            int n = wv * 32 + nf * 16 + lr;
            bf16x8 bh = *(const bf16x8*)(Wh + (size_t)n * DIM + c);
            bf16x8 bl = *(const bf16x8*)(Wl + (size_t)n * DIM + c);
            acc[0][nf] = MFMA_BF16(a0h, bh, acc[0][nf], 0, 0, 0);
            acc[0][nf] = MFMA_BF16(a0l, bh, acc[0][nf], 0, 0, 0);
            acc[0][nf] = MFMA_BF16(a0h, bl, acc[0][nf], 0, 0, 0);
            acc[1][nf] = MFMA_BF16(a1h, bh, acc[1][nf], 0, 0, 0);
            acc[1][nf] = MFMA_BF16(a1l, bh, acc[1][nf], 0, 0, 0);
            acc[1][nf] = MFMA_BF16(a1h, bl, acc[1][nf], 0, 0, 0);
        }
    }

    float as0 = a_s[wv * 32 + lr], as1 = a_s[wv * 32 + 16 + lr];
    float ad0 = a_d[wv * 32 + lr], ad1 = a_d[wv * 32 + 16 + lr];
#pragma unroll
    for (int mf = 0; mf < 2; mf++) {
#pragma unroll
        for (int r = 0; r < 4; r++) {
            int m = mf * 16 + lk * 4 + r;
            int node = n0 + m;
            float v0 = acc[mf][0][r], v1 = acc[mf][1][r];
            if (node < NODES) {
                hg[(size_t)node * DIM + wv * 32 + lr] = v0;
                hg[(size_t)node * DIM + wv * 32 + 16 + lr] = v1;
            }
            float ps = v0 * as0 + v1 * as1;
            float pd = v0 * ad0 + v1 * ad1;
#pragma unroll
            for (int off = 8; off > 0; off >>= 1) {
                ps += __shfl_xor(ps, off, 64);
                pd += __shfl_xor(pd, off, 64);
            }
            if (lr == 0 && node < NODES) {
                als[node * HEADS + wv] = ps;
                ald[node * HEADS + wv] = pd;
            }
        }
    }
}

// ---------- GAT aggregate + bias + residual + LN (4-deep edge pipeline) ----------
__global__ void k_agg(const float* __restrict__ x, const float* __restrict__ hg,
                      const float* __restrict__ als, const float* __restrict__ ald,
                      const int* __restrict__ rp, const int* __restrict__ ci,
                      const float* __restrict__ bias, const float* __restrict__ g,
                      const float* __restrict__ b, float* __restrict__ y) {
    __shared__ float red[4];
    int n = blockIdx.x, j = threadIdx.x, head = j >> 5;
    float aldn = ald[n * HEADS + head];
    float a0 = als[n * HEADS + head] + aldn;
    a0 = (a0 > 0.f) ? a0 : SLOPE * a0;
    float ex = __expf(a0);
    float den = ex;
    float acc = ex * hg[(size_t)n * DIM + j];
    int beg = rp[n], end = rp[n + 1];
    int e = beg;
    // 4-deep pipeline: batch index loads -> logit loads -> exps -> 4 independent row gathers
    for (; e + 4 <= end; e += 4) {
        int s0 = ci[e], s1 = ci[e + 1], s2 = ci[e + 2], s3 = ci[e + 3];
        float av0 = als[s0 * HEADS + head] + aldn;
        float av1 = als[s1 * HEADS + head] + aldn;
        float av2 = als[s2 * HEADS + head] + aldn;
        float av3 = als[s3 * HEADS + head] + aldn;
        av0 = (av0 > 0.f) ? av0 : SLOPE * av0;
        av1 = (av1 > 0.f) ? av1 : SLOPE * av1;
        av2 = (av2 > 0.f) ? av2 : SLOPE * av2;
        av3 = (av3 > 0.f) ? av3 : SLOPE * av3;
        float e0 = __expf(av0), e1 = __expf(av1), e2 = __expf(av2), e3 = __expf(av3);
        float h0 = hg[(size_t)s0 * DIM + j];
        float h1 = hg[(size_t)s1 * DIM + j];
        float h2 = hg[(size_t)s2 * DIM + j];
        float h3 = hg[(size_t)s3 * DIM + j];
        den += (e0 + e1) + (e2 + e3);
        acc += e0 * h0 + e1 * h1 + e2 * h2 + e3 * h3;
    }
    for (; e < end; e++) {
        int s = ci[e];
        float av = als[s * HEADS + head] + aldn;
        av = (av > 0.f) ? av : SLOPE * av;
        float e2 = __expf(av);
        den += e2;
        acc += e2 * hg[(size_t)s * DIM + j];
    }
    float val = x[(size_t)n * DIM + j] + acc / den + bias[j];
    float mean, rstd;
    ln_stats128(val, red, mean, rstd);
    y[(size_t)n * DIM + j] = (val - mean) * rstd * g[j] + b[j];
}

// ---------- split-bf16 MFMA fused FFN: x = LN(y + relu(y@W1+b1)@W2+b2) ----------
// R8/R10 512-thread version, EXACT (passing, frozen). Session laws: only
// correct at 1 block/CU (84KB LDS); 512 threads is the throughput optimum
// (1024-thread re-wave halved MfmaUtil — R11). Do not modify.
#define TM 32

__global__ void k_ffn_mfma(
    const float* __restrict__ yin,
    const unsigned short* __restrict__ W1h, const unsigned short* __restrict__ W1l,
    const float* __restrict__ b1,
    const unsigned short* __restrict__ W2h, const unsigned short* __restrict__ W2l,
    const float* __restrict__ b2, const float* __restrict__ g,
    const float* __restrict__ b, float* __restrict__ xout) {
    __shared__ __align__(16) unsigned char smem[(2 * TM * XS_STRIDE + 2 * TM * HID_STRIDE) * 2];
    unsigned short* xsh = (unsigned short*)smem;        // [32][136] bf16 hi
    unsigned short* xsl = xsh + TM * XS_STRIDE;         // [32][136] bf16 lo
    unsigned short* hidh = xsl + TM * XS_STRIDE;        // [32][520] bf16 hi
    unsigned short* hidl = hidh + TM * HID_STRIDE;      // [32][520] bf16 lo
    float* fbuf = (float*)hidh;                         // reuse: [32][132] fp32

    int t = threadIdx.x;  // 512
    int n0 = blockIdx.x * TM;

    // stage yin tile -> split bf16 LDS (1024 float4s = 32 rows x 32 float4)
#pragma unroll
    for (int jj = 0; jj < 2; jj++) {
        int v = t + jj * 512;
        int m = v >> 5, c4 = (v & 31) * 4;
        int node = n0 + m;
        float4 f;
        if (node < NODES) f = *(const float4*)(yin + (size_t)node * DIM + c4);
        else { f.x = f.y = f.z = f.w = 0.f; }
        us4 uh = {f2bf(f.x), f2bf(f.y), f2bf(f.z), f2bf(f.w)};
        us4 ul = {f2bf(f.x - bf2f(uh.x)), f2bf(f.y - bf2f(uh.y)),
                  f2bf(f.z - bf2f(uh.z)), f2bf(f.w - bf2f(uh.w))};
        *(us4*)(xsh + m * XS_STRIDE + c4) = uh;
        *(us4*)(xsl + m * XS_STRIDE + c4) = ul;
    }
    __syncthreads();

    int wv = t >> 6, l = t & 63, lr = l & 15, lk = l >> 4;  // wv in [0,8)

    // phase 1: hid = relu(xs @ W1 + b1); wave wv owns hidden cols [wv*64, wv*64+64)
    {
        f32x4 acc[2][4];
#pragma unroll
        for (int mf = 0; mf < 2; mf++)
#pragma unroll
            for (int nf = 0; nf < 4; nf++) acc[mf][nf] = (f32x4){0.f, 0.f, 0.f, 0.f};
#pragma unroll
        for (int kk = 0; kk < 4; kk++) {
            int c = kk * 32 + lk * 8;
            bf16x8 a0h = *(const bf16x8*)(xsh + lr * XS_STRIDE + c);
            bf16x8 a0l = *(const bf16x8*)(xsl + lr * XS_STRIDE + c);
            bf16x8 a1h = *(const bf16x8*)(xsh + (16 + lr) * XS_STRIDE + c);
            bf16x8 a1l = *(const bf16x8*)(xsl + (16 + lr) * XS_STRIDE + c);
#pragma unroll
            for (int nf = 0; nf < 4; nf++) {
                int n = wv * 64 + nf * 16 + lr;
                bf16x8 bh = *(const bf16x8*)(W1h + (size_t)n * DIM + c);
                bf16x8 bl = *(const bf16x8*)(W1l + (size_t)n * DIM + c);
                acc[0][nf] = MFMA_BF16(a0h, bh, acc[0][nf], 0, 0, 0);
                acc[0][nf] = MFMA_BF16(a0l, bh, acc[0][nf], 0, 0, 0);
                acc[0][nf] = MFMA_BF16(a0h, bl, acc[0][nf], 0, 0, 0);
                acc[1][nf] = MFMA_BF16(a1h, bh, acc[1][nf], 0, 0, 0);
                acc[1][nf] = MFMA_BF16(a1l, bh, acc[1][nf], 0, 0, 0);
                acc[1][nf] = MFMA_BF16(a1h, bl, acc[1][nf], 0, 0, 0);
            }
        }
#pragma unroll
        for (int nf = 0; nf < 4; nf++) {
            int n = wv * 64 + nf * 16 + lr;
            float bias = b1[n];
#pragma unroll
            for (int mf = 0; mf < 2; mf++)
#pragma unroll
                for (int r = 0; r < 4; r++) {
                    int m = mf * 16 + lk * 4 + r;
                    float val = fmaxf(acc[mf][nf][r] + bias, 0.f);
                    unsigned short h = f2bf(val);
                    hidh[m * HID_STRIDE + n] = h;
                    hidl[m * HID_STRIDE + n] = f2bf(val - bf2f(h));
                }
        }
    }
    __syncthreads();

    // phase 2: f = hid @ W2; wave wv owns out cols [wv*16, wv*16+16)
    f32x4 acc2[2];
#pragma unroll
    for (int mf = 0; mf < 2; mf++) acc2[mf] = (f32x4){0.f, 0.f, 0.f, 0.f};
#pragma unroll
    for (int kk = 0; kk < 16; kk++) {
        int c = kk * 32 + lk * 8;
        bf16x8 a0h = *(const bf16x8*)(hidh + lr * HID_STRIDE + c);
        bf16x8 a0l = *(const bf16x8*)(hidl + lr * HID_STRIDE + c);
        bf16x8 a1h = *(const bf16x8*)(hidh + (16 + lr) * HID_STRIDE + c);
        bf16x8 a1l = *(const bf16x8*)(hidl + (16 + lr) * HID_STRIDE + c);
        int n = wv * 16 + lr;
        bf16x8 bh = *(const bf16x8*)(W2h + (size_t)n * FFDIM + c);
        bf16x8 bl = *(const bf16x8*)(W2l + (size_t)n * FFDIM + c);
        acc2[0] = MFMA_BF16(a0h, bh, acc2[0], 0, 0, 0);
        acc2[0] = MFMA_BF16(a0l, bh, acc2[0], 0, 0, 0);
        acc2[0] = MFMA_BF16(a0h, bl, acc2[0], 0, 0, 0);
        acc2[1] = MFMA_BF16(a1h, bh, acc2[1], 0, 0, 0);
        acc2[1] = MFMA_BF16(a1l, bh, acc2[1], 0, 0, 0);
        acc2[1] = MFMA_BF16(a1h, bl, acc2[1], 0, 0, 0);
    }
    __syncthreads();  // all hid reads done before fbuf overwrite

    // residual + bias into fp32 LDS
    {
        int n = wv * 16 + lr;
        float bias = b2[n];
#pragma unroll
        for (int mf = 0; mf < 2; mf++)
#pragma unroll
            for (int r = 0; r < 4; r++) {
                int m = mf * 16 + lk * 4 + r;
                int node = n0 + m;
                float yv = (node < NODES) ? yin[(size_t)node * DIM + n] : 0.f;
                fbuf[m * FB_STRIDE + n] = acc2[mf][r] + bias + yv;
            }
    }
    __syncthreads();

    // LN: 16 threads per row, 8 cols each (512 threads / 32 rows)
    {
        int row = t >> 4, l16 = t & 15;
        float4 vv[2];
        float s1 = 0.f, s2 = 0.f;
#pragma unroll
        for (int q = 0; q < 2; q++) {
            vv[q] = *(float4*)(fbuf + row * FB_STRIDE + l16 * 8 + q * 4);
            s1 += vv[q].x + vv[q].y + vv[q].z + vv[q].w;
            s2 += vv[q].x * vv[q].x + vv[q].y * vv[q].y + vv[q].z * vv[q].z + vv[q].w * vv[q].w;
        }
#pragma unroll
        for (int off = 8; off > 0; off >>= 1) {
            s1 += __shfl_xor(s1, off, 64);
            s2 += __shfl_xor(s2, off, 64);
        }
        float mean = s1 * (1.f / 128.f);
        float var = s2 * (1.f / 128.f) - mean * mean;
        float rstd = rsqrtf(var + LN_EPS);
        int node = n0 + row;
        if (node < NODES) {
#pragma unroll
            for (int q = 0; q < 2; q++) {
                int c = l16 * 8 + q * 4;
                float4 gv = *(const float4*)(g + c);
                float4 bv = *(const float4*)(b + c);
                float4 o;
                o.x = (vv[q].x - mean) * rstd * gv.x + bv.x;
                o.y = (vv[q].y - mean) * rstd * gv.y + bv.y;
                o.z = (vv[q].z - mean) * rstd * gv.z + bv.z;
                o.w = (vv[q].w - mean) * rstd * gv.w + bv.w;
                *(float4*)(xout + (size_t)node * DIM + c) = o;
            }
        }
    }
}

// ---------- split-bf16 MFMA predictor precompute: P,Q (bf16) ----------
// Structure identical to the passing k_xw_mfma (multi-block-safe family);
// combined weight [512][128]: rows 0-255 -> P (bias be1), 256-511 -> Q.
// Wave wv owns output cols [wv*128, wv*128+128): waves 0-1 -> P, 2-3 -> Q.
__global__ void k_pq_mfma(const float* __restrict__ x,
                          const unsigned short* __restrict__ Wh,
                          const unsigned short* __restrict__ Wl,
                          const float* __restrict__ be1,
                          __hip_bfloat16* __restrict__ P, __hip_bfloat16* __restrict__ Q) {
    __shared__ __align__(16) unsigned short xsh[32 * XS_STRIDE];
    __shared__ __align__(16) unsigned short xsl[32 * XS_STRIDE];
    int t = threadIdx.x;
    int n0 = blockIdx.x * 32;

#pragma unroll
    for (int jj = 0; jj < 4; jj++) {
        int v = t + jj * 256;
        int m = v >> 5, c4 = (v & 31) * 4;
        int node = n0 + m;
        float4 f;
        if (node < NODES) f = *(const float4*)(x + (size_t)node * DIM + c4);
        else { f.x = f.y = f.z = f.w = 0.f; }
        us4 uh = {f2bf(f.x), f2bf(f.y), f2bf(f.z), f2bf(f.w)};
        us4 ul = {f2bf(f.x - bf2f(uh.x)), f2bf(f.y - bf2f(uh.y)),
                  f2bf(f.z - bf2f(uh.z)), f2bf(f.w - bf2f(uh.w))};
        *(us4*)(xsh + m * XS_STRIDE + c4) = uh;
        *(us4*)(xsl + m * XS_STRIDE + c4) = ul;
    }
    __syncthreads();

    int wv = t >> 6, l = t & 63, lr = l & 15, lk = l >> 4;

    f32x4 acc[2][8];
#pragma unroll
    for (int mf = 0; mf < 2; mf++)
#pragma unroll
        for (int nf = 0; nf < 8; nf++) acc[mf][nf] = (f32x4){0.f, 0.f, 0.f, 0.f};
#pragma unroll
    for (int kk = 0; kk < 4; kk++) {
        int c = kk * 32 + lk * 8;
        bf16x8 a0h = *(const bf16x8*)(xsh + lr * XS_STRIDE + c);
        bf16x8 a0l = *(const bf16x8*)(xsl + lr * XS_STRIDE + c);
        bf16x8 a1h = *(const bf16x8*)(xsh + (16 + lr) * XS_STRIDE + c);
        bf16x8 a1l = *(const bf16x8*)(xsl + (16 + lr) * XS_STRIDE + c);
#pragma unroll
        for (int nf = 0; nf < 8; nf++) {
            int n = wv * 128 + nf * 16 + lr;
            bf16x8 bh = *(const bf16x8*)(Wh + (size_t)n * DIM + c);
            bf16x8 bl = *(const bf16x8*)(Wl + (size_t)n * DIM + c);
            acc[0][nf] = MFMA_BF16(a0h, bh, acc[0][nf], 0, 0, 0);
            acc[0][nf] = MFMA_BF16(a0l, bh, acc[0][nf], 0, 0, 0);
            acc[0][nf] = MFMA_BF16(a0h, bl, acc[0][nf], 0, 0, 0);
            acc[1][nf] = MFMA_BF16(a1h, bh, acc[1][nf], 0, 0, 0);
            acc[1][nf] = MFMA_BF16(a1l, bh, acc[1][nf], 0, 0, 0);
            acc[1][nf] = MFMA_BF16(a1h, bl, acc[1][nf], 0, 0, 0);
        }
    }

#pragma unroll
    for (int nf = 0; nf < 8; nf++) {
        int n = wv * 128 + nf * 16 + lr;     // [0,512)
        float bias = (n < PHDIM) ? be1[n] : 0.f;
        __hip_bfloat16* dst = (n < PHDIM) ? P : Q;   // wave-uniform
        int col = n & (PHDIM - 1);
#pragma unroll
        for (int mf = 0; mf < 2; mf++)
#pragma unroll
            for (int r = 0; r < 4; r++) {
                int m = mf * 16 + lk * 4 + r;
                int node = n0 + m;
                if (node < NODES)
                    dst[(size_t)node * PHDIM + col] = __float2bfloat16(acc[mf][nf][r] + bias);
            }
    }
}

// ---------- edge predictor: flow = relu(relu(P[s]+Q[d]) . We2 + be2) ----------
__global__ void k_edge(const int* __restrict__ ei, const __hip_bfloat16* __restrict__ P,
                       const __hip_bfloat16* __restrict__ Q, const float* __restrict__ We2,
                       const float* __restrict__ be2, float* __restrict__ out) {
    int lane = threadIdx.x & 63;
    int wv = threadIdx.x >> 6;
    int e = blockIdx.x * 4 + wv;
    if (e >= NEDGE) return;
    float4 w2 = ((const float4*)We2)[lane];
    int s = ei[e], d = ei[NEDGE + e];
    uint2 pu = ((const uint2*)P)[(size_t)s * 64 + lane];
    uint2 qu = ((const uint2*)Q)[(size_t)d * 64 + lane];
    float p0 = __uint_as_float(pu.x << 16);
    float p1 = __uint_as_float(pu.x & 0xffff0000u);
    float p2 = __uint_as_float(pu.y << 16);
    float p3 = __uint_as_float(pu.y & 0xffff0000u);
    float q0 = __uint_as_float(qu.x << 16);
    float q1 = __uint_as_float(qu.x & 0xffff0000u);
    float q2 = __uint_as_float(qu.y << 16);
    float q3 = __uint_as_float(qu.y & 0xffff0000u);
    float acc = fmaxf(p0 + q0, 0.f) * w2.x + fmaxf(p1 + q1, 0.f) * w2.y +
                fmaxf(p2 + q2, 0.f) * w2.z + fmaxf(p3 + q3, 0.f) * w2.w;
#pragma unroll
    for (int off = 32; off > 0; off >>= 1) acc += __shfl_xor(acc, off, 64);
    if (lane == 0) out[e] = fmaxf(acc + be2[0], 0.f);
}

extern "C" void kernel_launch(void* const* d_in, const int* in_sizes, int n_in,
                              void* d_out, int out_size, void* d_ws, size_t ws_size,
                              hipStream_t stream) {
    const float* x0   = (const float*)d_in[0];
    const int*   eiR  = (const int*)d_in[1];
    const int*   eiV  = (const int*)d_in[2];
    const float* Wp   = (const float*)d_in[3];
    const float* bp   = (const float*)d_in[4];
    const float* lnpg = (const float*)d_in[5];
    const float* lnpb = (const float*)d_in[6];
    const float* vW   = (const float*)d_in[7];
    const float* v_as = (const float*)d_in[8];
    const float* v_ad = (const float*)d_in[9];
    const float* v_b  = (const float*)d_in[10];
    const float* vW1  = (const float*)d_in[11];
    const float* vb1  = (const float*)d_in[12];
    const float* vW2  = (const float*)d_in[13];
    const float* vb2  = (const float*)d_in[14];
    const float* vln1g = (const float*)d_in[15];
    const float* vln1b = (const float*)d_in[16];
    const float* vln2g = (const float*)d_in[17];
    const float* vln2b = (const float*)d_in[18];
    const float* rW   = (const float*)d_in[19];
    const float* r_as = (const float*)d_in[20];
    const float* r_ad = (const float*)d_in[21];
    const float* r_b  = (const float*)d_in[22];
    const float* rW1  = (const float*)d_in[23];
    const float* rb1  = (const float*)d_in[24];
    const float* rW2  = (const float*)d_in[25];
    const float* rb2  = (const float*)d_in[26];
    const float* rln1g = (const float*)d_in[27];
    const float* rln1b = (const float*)d_in[28];
    const float* rln2g = (const float*)d_in[29];
    const float* rln2b = (const float*)d_in[30];
    const float* We1  = (const float*)d_in[31];
    const float* be1  = (const float*)d_in[32];
    const float* We2  = (const float*)d_in[33];
    const float* be2  = (const float*)d_in[34];
    float* out = (float*)d_out;

    // workspace layout (16B-aligned segments first)
    float* X   = (float*)d_ws;                       // N*DIM
    float* Y   = X + (size_t)NODES * DIM;            // N*DIM
    float* HG  = Y + (size_t)NODES * DIM;            // N*DIM
    float* ALS = HG + (size_t)NODES * DIM;           // N*HEADS
    float* ALD = ALS + (size_t)NODES * HEADS;        // N*HEADS
    __hip_bfloat16* Pb = (__hip_bfloat16*)(ALD + (size_t)NODES * HEADS);  // N*PHDIM bf16
    __hip_bfloat16* Qb = Pb + (size_t)NODES * PHDIM;                      // N*PHDIM bf16
    // per layer: W1h, W1l, W2h, W2l each 65536 bf16
    unsigned short* WT = (unsigned short*)(Qb + (size_t)NODES * PHDIM);   // 4*4*65536 bf16
    // per layer: GAT W hi/lo each 16384 bf16
    unsigned short* WXT = WT + (size_t)4 * 4 * 65536;                     // 4*2*16384 bf16
    // predictor combined weight [512][128] hi/lo
    unsigned short* WPQ = WXT + (size_t)4 * 2 * 16384;                    // 2*65536 bf16
    int* rpV = (int*)(WPQ + (size_t)2 * 65536);      // N+1
    int* ciV = rpV + (NODES + 1);                    // E
    int* rpR = ciV + NEDGE;                          // N+1
    int* ciR = rpR + (NODES + 1);                    // E
    int* cnt = ciR + NEDGE;                          // N

    const int EB = (NEDGE + 255) / 256;

    // CSR for virtual graph
    hipMemsetAsync(cnt, 0, sizeof(int) * NODES, stream);
    k_count<<<EB, 256, 0, stream>>>(eiV + NEDGE, cnt);
    k_scan<<<1, 1024, 0, stream>>>(cnt, rpV);
    hipMemsetAsync(cnt, 0, sizeof(int) * NODES, stream);
    k_fill<<<EB, 256, 0, stream>>>(eiV, rpV, cnt, ciV);
    // CSR for real graph
    hipMemsetAsync(cnt, 0, sizeof(int) * NODES, stream);
    k_count<<<EB, 256, 0, stream>>>(eiR + NEDGE, cnt);
    k_scan<<<1, 1024, 0, stream>>>(cnt, rpR);
    hipMemsetAsync(cnt, 0, sizeof(int) * NODES, stream);
    k_fill<<<EB, 256, 0, stream>>>(eiR, rpR, cnt, ciR);

    // weight transpose + split-bf16 (once per launch; L2-resident afterwards)
    for (int l = 0; l < 4; l++) {
        bool virt = (l < 2);
        int i = virt ? l : (l - 2);
        const float* W1 = (virt ? vW1 : rW1) + (size_t)i * DIM * FFDIM;
        const float* W2 = (virt ? vW2 : rW2) + (size_t)i * FFDIM * DIM;
        const float* W  = (virt ? vW : rW) + (size_t)i * DIM * DIM;
        unsigned short* base = WT + (size_t)l * 262144;
        k_wcvt2<DIM, FFDIM><<<256, 256, 0, stream>>>(W1, base, base + 65536);            // W1T[512][128] hi/lo
        k_wcvt2<FFDIM, DIM><<<256, 256, 0, stream>>>(W2, base + 131072, base + 196608);  // W2T[128][512] hi/lo
        unsigned short* bx = WXT + (size_t)l * 32768;
        k_wcvt2<DIM, DIM><<<64, 256, 0, stream>>>(W, bx, bx + 16384);                    // WT[128][128] hi/lo
    }
    k_wcvt_pq<<<256, 256, 0, stream>>>(We1, WPQ, WPQ + 65536);                           // [512][128] hi/lo

    // preprocessing
    k_preprocess<<<NODES, 128, 0, stream>>>(x0, Wp, bp, lnpg, lnpb, X);

    // 4 encoder layers: 2 virtual, 2 real
    for (int l = 0; l < 4; l++) {
        bool virt = (l < 2);
        int i = virt ? l : (l - 2);
        const float* As = (virt ? v_as : r_as) + (size_t)i * HEADS * CHC;
        const float* Ad = (virt ? v_ad : r_ad) + (size_t)i * HEADS * CHC;
        const float* Bb = (virt ? v_b : r_b) + (size_t)i * DIM;
        const float* B1 = (virt ? vb1 : rb1) + (size_t)i * FFDIM;
        const float* B2 = (virt ? vb2 : rb2) + (size_t)i * DIM;
        const float* G1 = (virt ? vln1g : rln1g) + (size_t)i * DIM;
        const float* B1n = (virt ? vln1b : rln1b) + (size_t)i * DIM;
        const float* G2 = (virt ? vln2g : rln2g) + (size_t)i * DIM;
        const float* B2n = (virt ? vln2b : rln2b) + (size_t)i * DIM;
        const int* rp = virt ? rpV : rpR;
        const int* ci = virt ? ciV : ciR;

        unsigned short* bx = WXT + (size_t)l * 32768;
        k_xw_mfma<<<(NODES + 31) / 32, 256, 0, stream>>>(X, bx, bx + 16384, As, Ad, HG, ALS, ALD);
        k_agg<<<NODES, 128, 0, stream>>>(X, HG, ALS, ALD, rp, ci, Bb, G1, B1n, Y);
        unsigned short* base = WT + (size_t)l * 262144;
        k_ffn_mfma<<<(NODES + TM - 1) / TM, 512, 0, stream>>>(
            Y, base, base + 65536, B1, base + 131072, base + 196608, B2, G2, B2n, X);
    }

    // edge predictor
    k_pq_mfma<<<(NODES + 31) / 32, 256, 0, stream>>>(X, WPQ, WPQ + 65536, be1, Pb, Qb);
    k_edge<<<(NEDGE + 3) / 4, 256, 0, stream>>>(eiR, Pb, Qb, We2, be2, out);
}

// Round 13
// 1372.034 us; speedup vs baseline: 1.2976x; 1.0167x over previous
//
#include <hip/hip_runtime.h>
#include <hip/hip_bf16.h>
#include <math.h>

#define NODES 50000
#define NFEAT 64
#define DIM 128
#define HEADS 4
#define CHC 32
#define FFDIM 512
#define PHDIM 256
#define NEDGE 600000
#define LN_EPS 1e-5f
#define SLOPE 0.2f

typedef __attribute__((ext_vector_type(8))) short bf16x8;
typedef __attribute__((ext_vector_type(4))) float f32x4;
typedef __attribute__((ext_vector_type(4))) unsigned short us4;

__device__ __forceinline__ unsigned short f2bf(float f) {
    __hip_bfloat16 h = __float2bfloat16(f);
    return reinterpret_cast<unsigned short&>(h);
}
__device__ __forceinline__ float bf2f(unsigned short u) {
    return __uint_as_float(((unsigned int)u) << 16);
}

// ---------- helpers ----------
__device__ __forceinline__ void ln_stats128(float val, float* red, float& mean, float& rstd) {
    float s1 = val, s2 = val * val;
#pragma unroll
    for (int off = 32; off > 0; off >>= 1) {
        s1 += __shfl_xor(s1, off, 64);
        s2 += __shfl_xor(s2, off, 64);
    }
    int wv = threadIdx.x >> 6;
    if ((threadIdx.x & 63) == 0) { red[wv * 2] = s1; red[wv * 2 + 1] = s2; }
    __syncthreads();
    float t1 = red[0] + red[2];
    float t2 = red[1] + red[3];
    mean = t1 * (1.f / 128.f);
    float var = t2 * (1.f / 128.f) - mean * mean;
    rstd = rsqrtf(var + LN_EPS);
}

// ---------- CSR build ----------
__global__ void k_count(const int* __restrict__ dst, int* __restrict__ cnt) {
    int e = blockIdx.x * 256 + threadIdx.x;
    if (e < NEDGE) atomicAdd(&cnt[dst[e]], 1);
}

__global__ void k_scan(const int* __restrict__ deg, int* __restrict__ rp) {
    __shared__ int sh[1024];
    int t = threadIdx.x;
    const int per = (NODES + 1023) / 1024;
    int beg = t * per;
    int end = beg + per; if (end > NODES) end = NODES; if (beg > NODES) beg = NODES;
    int s = 0;
    for (int i = beg; i < end; i++) s += deg[i];
    sh[t] = s;
    __syncthreads();
    for (int off = 1; off < 1024; off <<= 1) {
        int v = (t >= off) ? sh[t - off] : 0;
        __syncthreads();
        sh[t] += v;
        __syncthreads();
    }
    int run = sh[t] - s;  // exclusive prefix
    for (int i = beg; i < end; i++) { rp[i] = run; run += deg[i]; }
    if (t == 1023) rp[NODES] = sh[1023];
}

__global__ void k_fill(const int* __restrict__ ei, const int* __restrict__ rp,
                       int* __restrict__ cnt, int* __restrict__ ci) {
    int e = blockIdx.x * 256 + threadIdx.x;
    if (e < NEDGE) {
        int s = ei[e], d = ei[NEDGE + e];
        int pos = atomicAdd(&cnt[d], 1);
        ci[rp[d] + pos] = s;
    }
}

// ---------- weight transpose + split-bf16 convert: hi/lo of in[k*NR+n] ----------
template <int KI, int NR>
__global__ void k_wcvt2(const float* __restrict__ in, unsigned short* __restrict__ oh,
                        unsigned short* __restrict__ ol) {
    int tid = blockIdx.x * 256 + threadIdx.x;  // KI*NR total
    int n = tid / KI, k = tid % KI;
    float w = in[k * NR + n];
    unsigned short h = f2bf(w);
    oh[tid] = h;
    ol[tid] = f2bf(w - bf2f(h));
}

// We1 [2*DIM][PHDIM] -> combined [512][128] hi/lo: rows 0-255 = P cols (We1 top),
// rows 256-511 = Q cols (We1 bottom)
__global__ void k_wcvt_pq(const float* __restrict__ We1, unsigned short* __restrict__ oh,
                          unsigned short* __restrict__ ol) {
    int tid = blockIdx.x * 256 + threadIdx.x;  // 512*128
    int n = tid >> 7, k = tid & 127;
    float w = (n < PHDIM) ? We1[k * PHDIM + n] : We1[(DIM + k) * PHDIM + (n - PHDIM)];
    unsigned short h = f2bf(w);
    oh[tid] = h;
    ol[tid] = f2bf(w - bf2f(h));
}

// ---------- preprocessing: x = LN(relu(x0 @ Wp + bp)) ----------
__global__ void k_preprocess(const float* __restrict__ x0, const float* __restrict__ Wp,
                             const float* __restrict__ bp, const float* __restrict__ g,
                             const float* __restrict__ b, float* __restrict__ xout) {
    __shared__ float xr[NFEAT];
    __shared__ float red[4];
    int n = blockIdx.x;
    int j = threadIdx.x;
    if (j < NFEAT) xr[j] = x0[n * NFEAT + j];
    __syncthreads();
    float acc = bp[j];
#pragma unroll
    for (int k = 0; k < NFEAT; k++) acc += xr[k] * Wp[k * DIM + j];
    acc = fmaxf(acc, 0.f);
    float mean, rstd;
    ln_stats128(acc, red, mean, rstd);
    xout[n * DIM + j] = (acc - mean) * rstd * g[j] + b[j];
}

#define XS_STRIDE 136   // 128 + 8 bf16 pad (272 B rows, 16B-aligned)
#define HID_STRIDE 520  // 512 + 8 bf16 pad (1040 B rows)
#define FB_STRIDE 132   // fp32 resid buffer stride
#define MFMA_BF16 __builtin_amdgcn_mfma_f32_16x16x32_bf16

// ---------- split-bf16 MFMA: hg = x @ W (bf16 out) ; fused attention logits ----------
// NO __launch_bounds__ on split-bf16 MFMA kernels (session finding).
__global__ void k_xw_mfma(const float* __restrict__ x,
                          const unsigned short* __restrict__ Wh,
                          const unsigned short* __restrict__ Wl,
                          const float* __restrict__ a_s, const float* __restrict__ a_d,
                          unsigned short* __restrict__ hg, float* __restrict__ als,
                          float* __restrict__ ald) {
    __shared__ __align__(16) unsigned short xsh[32 * XS_STRIDE];
    __shared__ __align__(16) unsigned short xsl[32 * XS_STRIDE];
    int t = threadIdx.x;
    int n0 = blockIdx.x * 32;

#pragma unroll
    for (int jj = 0; jj < 4; jj++) {
        int v = t + jj * 256;  // 1024 float4s = 32 rows x 32 float4
        int m = v >> 5, c4 = (v & 31) * 4;
        int node = n0 + m;
        float4 f;
        if (node < NODES) f = *(const float4*)(x + (size_t)node * DIM + c4);
        else { f.x = f.y = f.z = f.w = 0.f; }
        us4 uh = {f2bf(f.x), f2bf(f.y), f2bf(f.z), f2bf(f.w)};
        us4 ul = {f2bf(f.x - bf2f(uh.x)), f2bf(f.y - bf2f(uh.y)),
                  f2bf(f.z - bf2f(uh.z)), f2bf(f.w - bf2f(uh.w))};
        *(us4*)(xsh + m * XS_STRIDE + c4) = uh;
        *(us4*)(xsl + m * XS_STRIDE + c4) = ul;
    }
    __syncthreads();

    int wv = t >> 6, l = t & 63, lr = l & 15, lk = l >> 4;

    f32x4 acc[2][2];
#pragma unroll
    for (int mf = 0; mf < 2; mf++)
#pragma unroll
        for (int nf = 0; nf < 2; nf++) acc[mf][nf] = (f32x4){0.f, 0.f, 0.f, 0.f};
#pragma unroll
    for (int kk = 0; kk < 4; kk++) {
        int c = kk * 32 + lk * 8;
        bf16x8 a0h = *(const bf16x8*)(xsh + lr * XS_STRIDE + c);
        bf16x8 a0l = *(const bf16x8*)(xsl + lr * XS_STRIDE + c);
        bf16x8 a1h = *(const bf16x8*)(xsh + (16 + lr) * XS_STRIDE + c);
        bf16x8 a1l = *(const bf16x8*)(xsl + (16 + lr) * XS_STRIDE + c);
#pragma unroll
        for (int nf = 0; nf < 2; nf++) {
            int n = wv * 32 + nf * 16 + lr;
            bf16x8 bh = *(const bf16x8*)(Wh + (size_t)n * DIM + c);
            bf16x8 bl = *(const bf16x8*)(Wl + (size_t)n * DIM + c);
            acc[0][nf] = MFMA_BF16(a0h, bh, acc[0][nf], 0, 0, 0);
            acc[0][nf] = MFMA_BF16(a0l, bh, acc[0][nf], 0, 0, 0);
            acc[0][nf] = MFMA_BF16(a0h, bl, acc[0][nf], 0, 0, 0);
            acc[1][nf] = MFMA_BF16(a1h, bh, acc[1][nf], 0, 0, 0);
            acc[1][nf] = MFMA_BF16(a1l, bh, acc[1][nf], 0, 0, 0);
            acc[1][nf] = MFMA_BF16(a1h, bl, acc[1][nf], 0, 0, 0);
        }
    }

    float as0 = a_s[wv * 32 + lr], as1 = a_s[wv * 32 + 16 + lr];
    float ad0 = a_d[wv * 32 + lr], ad1 = a_d[wv * 32 + 16 + lr];
#pragma unroll
    for (int mf = 0; mf < 2; mf++) {
#pragma unroll
        for (int r = 0; r < 4; r++) {
            int m = mf * 16 + lk * 4 + r;
            int node = n0 + m;
            float v0 = acc[mf][0][r], v1 = acc[mf][1][r];
            if (node < NODES) {
                hg[(size_t)node * DIM + wv * 32 + lr] = f2bf(v0);
                hg[(size_t)node * DIM + wv * 32 + 16 + lr] = f2bf(v1);
            }
            float ps = v0 * as0 + v1 * as1;
            float pd = v0 * ad0 + v1 * ad1;
#pragma unroll
            for (int off = 8; off > 0; off >>= 1) {
                ps += __shfl_xor(ps, off, 64);
                pd += __shfl_xor(pd, off, 64);
            }
            if (lr == 0 && node < NODES) {
                als[node * HEADS + wv] = ps;
                ald[node * HEADS + wv] = pd;
            }
        }
    }
}

// ---------- GAT aggregate + bias + residual + LN (4-deep edge pipeline, bf16 hg) ----------
__global__ void k_agg(const float* __restrict__ x, const unsigned short* __restrict__ hg,
                      const float* __restrict__ als, const float* __restrict__ ald,
                      const int* __restrict__ rp, const int* __restrict__ ci,
                      const float* __restrict__ bias, const float* __restrict__ g,
                      const float* __restrict__ b, float* __restrict__ y) {
    __shared__ float red[4];
    int n = blockIdx.x, j = threadIdx.x, head = j >> 5;
    float aldn = ald[n * HEADS + head];
    float a0 = als[n * HEADS + head] + aldn;
    a0 = (a0 > 0.f) ? a0 : SLOPE * a0;
    float ex = __expf(a0);
    float den = ex;
    float acc = ex * bf2f(hg[(size_t)n * DIM + j]);
    int beg = rp[n], end = rp[n + 1];
    int e = beg;
    // 4-deep pipeline: batch index loads -> logit loads -> exps -> 4 independent row gathers
    for (; e + 4 <= end; e += 4) {
        int s0 = ci[e], s1 = ci[e + 1], s2 = ci[e + 2], s3 = ci[e + 3];
        float av0 = als[s0 * HEADS + head] + aldn;
        float av1 = als[s1 * HEADS + head] + aldn;
        float av2 = als[s2 * HEADS + head] + aldn;
        float av3 = als[s3 * HEADS + head] + aldn;
        av0 = (av0 > 0.f) ? av0 : SLOPE * av0;
        av1 = (av1 > 0.f) ? av1 : SLOPE * av1;
        av2 = (av2 > 0.f) ? av2 : SLOPE * av2;
        av3 = (av3 > 0.f) ? av3 : SLOPE * av3;
        float e0 = __expf(av0), e1 = __expf(av1), e2 = __expf(av2), e3 = __expf(av3);
        float h0 = bf2f(hg[(size_t)s0 * DIM + j]);
        float h1 = bf2f(hg[(size_t)s1 * DIM + j]);
        float h2 = bf2f(hg[(size_t)s2 * DIM + j]);
        float h3 = bf2f(hg[(size_t)s3 * DIM + j]);
        den += (e0 + e1) + (e2 + e3);
        acc += e0 * h0 + e1 * h1 + e2 * h2 + e3 * h3;
    }
    for (; e < end; e++) {
        int s = ci[e];
        float av = als[s * HEADS + head] + aldn;
        av = (av > 0.f) ? av : SLOPE * av;
        float e2 = __expf(av);
        den += e2;
        acc += e2 * bf2f(hg[(size_t)s * DIM + j]);
    }
    float val = x[(size_t)n * DIM + j] + acc / den + bias[j];
    float mean, rstd;
    ln_stats128(val, red, mean, rstd);
    y[(size_t)n * DIM + j] = (val - mean) * rstd * g[j] + b[j];
}

// ---------- split-bf16 MFMA fused FFN: x = LN(y + relu(y@W1+b1)@W2+b2) ----------
// R8/R10 512-thread version, EXACT (passing, frozen). Session laws: only
// correct at 1 block/CU (84KB LDS); 512 threads is the throughput optimum
// (1024-thread re-wave halved MfmaUtil — R11). Do not modify.
#define TM 32

__global__ void k_ffn_mfma(
    const float* __restrict__ yin,
    const unsigned short* __restrict__ W1h, const unsigned short* __restrict__ W1l,
    const float* __restrict__ b1,
    const unsigned short* __restrict__ W2h, const unsigned short* __restrict__ W2l,
    const float* __restrict__ b2, const float* __restrict__ g,
    const float* __restrict__ b, float* __restrict__ xout) {
    __shared__ __align__(16) unsigned char smem[(2 * TM * XS_STRIDE + 2 * TM * HID_STRIDE) * 2];
    unsigned short* xsh = (unsigned short*)smem;        // [32][136] bf16 hi
    unsigned short* xsl = xsh + TM * XS_STRIDE;         // [32][136] bf16 lo
    unsigned short* hidh = xsl + TM * XS_STRIDE;        // [32][520] bf16 hi
    unsigned short* hidl = hidh + TM * HID_STRIDE;      // [32][520] bf16 lo
    float* fbuf = (float*)hidh;                         // reuse: [32][132] fp32

    int t = threadIdx.x;  // 512
    int n0 = blockIdx.x * TM;

    // stage yin tile -> split bf16 LDS (1024 float4s = 32 rows x 32 float4)
#pragma unroll
    for (int jj = 0; jj < 2; jj++) {
        int v = t + jj * 512;
        int m = v >> 5, c4 = (v & 31) * 4;
        int node = n0 + m;
        float4 f;
        if (node < NODES) f = *(const float4*)(yin + (size_t)node * DIM + c4);
        else { f.x = f.y = f.z = f.w = 0.f; }
        us4 uh = {f2bf(f.x), f2bf(f.y), f2bf(f.z), f2bf(f.w)};
        us4 ul = {f2bf(f.x - bf2f(uh.x)), f2bf(f.y - bf2f(uh.y)),
                  f2bf(f.z - bf2f(uh.z)), f2bf(f.w - bf2f(uh.w))};
        *(us4*)(xsh + m * XS_STRIDE + c4) = uh;
        *(us4*)(xsl + m * XS_STRIDE + c4) = ul;
    }
    __syncthreads();

    int wv = t >> 6, l = t & 63, lr = l & 15, lk = l >> 4;  // wv in [0,8)

    // phase 1: hid = relu(xs @ W1 + b1); wave wv owns hidden cols [wv*64, wv*64+64)
    {
        f32x4 acc[2][4];
#pragma unroll
        for (int mf = 0; mf < 2; mf++)
#pragma unroll
            for (int nf = 0; nf < 4; nf++) acc[mf][nf] = (f32x4){0.f, 0.f, 0.f, 0.f};
#pragma unroll
        for (int kk = 0; kk < 4; kk++) {
            int c = kk * 32 + lk * 8;
            bf16x8 a0h = *(const bf16x8*)(xsh + lr * XS_STRIDE + c);
            bf16x8 a0l = *(const bf16x8*)(xsl + lr * XS_STRIDE + c);
            bf16x8 a1h = *(const bf16x8*)(xsh + (16 + lr) * XS_STRIDE + c);
            bf16x8 a1l = *(const bf16x8*)(xsl + (16 + lr) * XS_STRIDE + c);
#pragma unroll
            for (int nf = 0; nf < 4; nf++) {
                int n = wv * 64 + nf * 16 + lr;
                bf16x8 bh = *(const bf16x8*)(W1h + (size_t)n * DIM + c);
                bf16x8 bl = *(const bf16x8*)(W1l + (size_t)n * DIM + c);
                acc[0][nf] = MFMA_BF16(a0h, bh, acc[0][nf], 0, 0, 0);
                acc[0][nf] = MFMA_BF16(a0l, bh, acc[0][nf], 0, 0, 0);
                acc[0][nf] = MFMA_BF16(a0h, bl, acc[0][nf], 0, 0, 0);
                acc[1][nf] = MFMA_BF16(a1h, bh, acc[1][nf], 0, 0, 0);
                acc[1][nf] = MFMA_BF16(a1l, bh, acc[1][nf], 0, 0, 0);
                acc[1][nf] = MFMA_BF16(a1h, bl, acc[1][nf], 0, 0, 0);
            }
        }
#pragma unroll
        for (int nf = 0; nf < 4; nf++) {
            int n = wv * 64 + nf * 16 + lr;
            float bias = b1[n];
#pragma unroll
            for (int mf = 0; mf < 2; mf++)
#pragma unroll
                for (int r = 0; r < 4; r++) {
                    int m = mf * 16 + lk * 4 + r;
                    float val = fmaxf(acc[mf][nf][r] + bias, 0.f);
                    unsigned short h = f2bf(val);
                    hidh[m * HID_STRIDE + n] = h;
                    hidl[m * HID_STRIDE + n] = f2bf(val - bf2f(h));
                }
        }
    }
    __syncthreads();

    // phase 2: f = hid @ W2; wave wv owns out cols [wv*16, wv*16+16)
    f32x4 acc2[2];
#pragma unroll
    for (int mf = 0; mf < 2; mf++) acc2[mf] = (f32x4){0.f, 0.f, 0.f, 0.f};
#pragma unroll
    for (int kk = 0; kk < 16; kk++) {
        int c = kk * 32 + lk * 8;
        bf16x8 a0h = *(const bf16x8*)(hidh + lr * HID_STRIDE + c);
        bf16x8 a0l = *(const bf16x8*)(hidl + lr * HID_STRIDE + c);
        bf16x8 a1h = *(const bf16x8*)(hidh + (16 + lr) * HID_STRIDE + c);
        bf16x8 a1l = *(const bf16x8*)(hidl + (16 + lr) * HID_STRIDE + c);
        int n = wv * 16 + lr;
        bf16x8 bh = *(const bf16x8*)(W2h + (size_t)n * FFDIM + c);
        bf16x8 bl = *(const bf16x8*)(W2l + (size_t)n * FFDIM + c);
        acc2[0] = MFMA_BF16(a0h, bh, acc2[0], 0, 0, 0);
        acc2[0] = MFMA_BF16(a0l, bh, acc2[0], 0, 0, 0);
        acc2[0] = MFMA_BF16(a0h, bl, acc2[0], 0, 0, 0);
        acc2[1] = MFMA_BF16(a1h, bh, acc2[1], 0, 0, 0);
        acc2[1] = MFMA_BF16(a1l, bh, acc2[1], 0, 0, 0);
        acc2[1] = MFMA_BF16(a1h, bl, acc2[1], 0, 0, 0);
    }
    __syncthreads();  // all hid reads done before fbuf overwrite

    // residual + bias into fp32 LDS
    {
        int n = wv * 16 + lr;
        float bias = b2[n];
#pragma unroll
        for (int mf = 0; mf < 2; mf++)
#pragma unroll
            for (int r = 0; r < 4; r++) {
                int m = mf * 16 + lk * 4 + r;
                int node = n0 + m;
                float yv = (node < NODES) ? yin[(size_t)node * DIM + n] : 0.f;
                fbuf[m * FB_STRIDE + n] = acc2[mf][r] + bias + yv;
            }
    }
    __syncthreads();

    // LN: 16 threads per row, 8 cols each (512 threads / 32 rows)
    {
        int row = t >> 4, l16 = t & 15;
        float4 vv[2];
        float s1 = 0.f, s2 = 0.f;
#pragma unroll
        for (int q = 0; q < 2; q++) {
            vv[q] = *(float4*)(fbuf + row * FB_STRIDE + l16 * 8 + q * 4);
            s1 += vv[q].x + vv[q].y + vv[q].z + vv[q].w;
            s2 += vv[q].x * vv[q].x + vv[q].y * vv[q].y + vv[q].z * vv[q].z + vv[q].w * vv[q].w;
        }
#pragma unroll
        for (int off = 8; off > 0; off >>= 1) {
            s1 += __shfl_xor(s1, off, 64);
            s2 += __shfl_xor(s2, off, 64);
        }
        float mean = s1 * (1.f / 128.f);
        float var = s2 * (1.f / 128.f) - mean * mean;
        float rstd = rsqrtf(var + LN_EPS);
        int node = n0 + row;
        if (node < NODES) {
#pragma unroll
            for (int q = 0; q < 2; q++) {
                int c = l16 * 8 + q * 4;
                float4 gv = *(const float4*)(g + c);
                float4 bv = *(const float4*)(b + c);
                float4 o;
                o.x = (vv[q].x - mean) * rstd * gv.x + bv.x;
                o.y = (vv[q].y - mean) * rstd * gv.y + bv.y;
                o.z = (vv[q].z - mean) * rstd * gv.z + bv.z;
                o.w = (vv[q].w - mean) * rstd * gv.w + bv.w;
                *(float4*)(xout + (size_t)node * DIM + c) = o;
            }
        }
    }
}

// ---------- split-bf16 MFMA predictor precompute: P,Q (bf16) ----------
__global__ void k_pq_mfma(const float* __restrict__ x,
                          const unsigned short* __restrict__ Wh,
                          const unsigned short* __restrict__ Wl,
                          const float* __restrict__ be1,
                          __hip_bfloat16* __restrict__ P, __hip_bfloat16* __restrict__ Q) {
    __shared__ __align__(16) unsigned short xsh[32 * XS_STRIDE];
    __shared__ __align__(16) unsigned short xsl[32 * XS_STRIDE];
    int t = threadIdx.x;
    int n0 = blockIdx.x * 32;

#pragma unroll
    for (int jj = 0; jj < 4; jj++) {
        int v = t + jj * 256;
        int m = v >> 5, c4 = (v & 31) * 4;
        int node = n0 + m;
        float4 f;
        if (node < NODES) f = *(const float4*)(x + (size_t)node * DIM + c4);
        else { f.x = f.y = f.z = f.w = 0.f; }
        us4 uh = {f2bf(f.x), f2bf(f.y), f2bf(f.z), f2bf(f.w)};
        us4 ul = {f2bf(f.x - bf2f(uh.x)), f2bf(f.y - bf2f(uh.y)),
                  f2bf(f.z - bf2f(uh.z)), f2bf(f.w - bf2f(uh.w))};
        *(us4*)(xsh + m * XS_STRIDE + c4) = uh;
        *(us4*)(xsl + m * XS_STRIDE + c4) = ul;
    }
    __syncthreads();

    int wv = t >> 6, l = t & 63, lr = l & 15, lk = l >> 4;

    f32x4 acc[2][8];
#pragma unroll
    for (int mf = 0; mf < 2; mf++)
#pragma unroll
        for (int nf = 0; nf < 8; nf++) acc[mf][nf] = (f32x4){0.f, 0.f, 0.f, 0.f};
#pragma unroll
    for (int kk = 0; kk < 4; kk++) {
        int c = kk * 32 + lk * 8;
        bf16x8 a0h = *(const bf16x8*)(xsh + lr * XS_STRIDE + c);
        bf16x8 a0l = *(const bf16x8*)(xsl + lr * XS_STRIDE + c);
        bf16x8 a1h = *(const bf16x8*)(xsh + (16 + lr) * XS_STRIDE + c);
        bf16x8 a1l = *(const bf16x8*)(xsl + (16 + lr) * XS_STRIDE + c);
#pragma unroll
        for (int nf = 0; nf < 8; nf++) {
            int n = wv * 128 + nf * 16 + lr;
            bf16x8 bh = *(const bf16x8*)(Wh + (size_t)n * DIM + c);
            bf16x8 bl = *(const bf16x8*)(Wl + (size_t)n * DIM + c);
            acc[0][nf] = MFMA_BF16(a0h, bh, acc[0][nf], 0, 0, 0);
            acc[0][nf] = MFMA_BF16(a0l, bh, acc[0][nf], 0, 0, 0);
            acc[0][nf] = MFMA_BF16(a0h, bl, acc[0][nf], 0, 0, 0);
            acc[1][nf] = MFMA_BF16(a1h, bh, acc[1][nf], 0, 0, 0);
            acc[1][nf] = MFMA_BF16(a1l, bh, acc[1][nf], 0, 0, 0);
            acc[1][nf] = MFMA_BF16(a1h, bl, acc[1][nf], 0, 0, 0);
        }
    }

#pragma unroll
    for (int nf = 0; nf < 8; nf++) {
        int n = wv * 128 + nf * 16 + lr;     // [0,512)
        float bias = (n < PHDIM) ? be1[n] : 0.f;
        __hip_bfloat16* dst = (n < PHDIM) ? P : Q;   // wave-uniform
        int col = n & (PHDIM - 1);
#pragma unroll
        for (int mf = 0; mf < 2; mf++)
#pragma unroll
            for (int r = 0; r < 4; r++) {
                int m = mf * 16 + lk * 4 + r;
                int node = n0 + m;
                if (node < NODES)
                    dst[(size_t)node * PHDIM + col] = __float2bfloat16(acc[mf][nf][r] + bias);
            }
    }
}

// ---------- edge predictor: flow = relu(relu(P[s]+Q[d]) . We2 + be2) ----------
__global__ void k_edge(const int* __restrict__ ei, const __hip_bfloat16* __restrict__ P,
                       const __hip_bfloat16* __restrict__ Q, const float* __restrict__ We2,
                       const float* __restrict__ be2, float* __restrict__ out) {
    int lane = threadIdx.x & 63;
    int wv = threadIdx.x >> 6;
    int e = blockIdx.x * 4 + wv;
    if (e >= NEDGE) return;
    float4 w2 = ((const float4*)We2)[lane];
    int s = ei[e], d = ei[NEDGE + e];
    uint2 pu = ((const uint2*)P)[(size_t)s * 64 + lane];
    uint2 qu = ((const uint2*)Q)[(size_t)d * 64 + lane];
    float p0 = __uint_as_float(pu.x << 16);
    float p1 = __uint_as_float(pu.x & 0xffff0000u);
    float p2 = __uint_as_float(pu.y << 16);
    float p3 = __uint_as_float(pu.y & 0xffff0000u);
    float q0 = __uint_as_float(qu.x << 16);
    float q1 = __uint_as_float(qu.x & 0xffff0000u);
    float q2 = __uint_as_float(qu.y << 16);
    float q3 = __uint_as_float(qu.y & 0xffff0000u);
    float acc = fmaxf(p0 + q0, 0.f) * w2.x + fmaxf(p1 + q1, 0.f) * w2.y +
                fmaxf(p2 + q2, 0.f) * w2.z + fmaxf(p3 + q3, 0.f) * w2.w;
#pragma unroll
    for (int off = 32; off > 0; off >>= 1) acc += __shfl_xor(acc, off, 64);
    if (lane == 0) out[e] = fmaxf(acc + be2[0], 0.f);
}

extern "C" void kernel_launch(void* const* d_in, const int* in_sizes, int n_in,
                              void* d_out, int out_size, void* d_ws, size_t ws_size,
                              hipStream_t stream) {
    const float* x0   = (const float*)d_in[0];
    const int*   eiR  = (const int*)d_in[1];
    const int*   eiV  = (const int*)d_in[2];
    const float* Wp   = (const float*)d_in[3];
    const float* bp   = (const float*)d_in[4];
    const float* lnpg = (const float*)d_in[5];
    const float* lnpb = (const float*)d_in[6];
    const float* vW   = (const float*)d_in[7];
    const float* v_as = (const float*)d_in[8];
    const float* v_ad = (const float*)d_in[9];
    const float* v_b  = (const float*)d_in[10];
    const float* vW1  = (const float*)d_in[11];
    const float* vb1  = (const float*)d_in[12];
    const float* vW2  = (const float*)d_in[13];
    const float* vb2  = (const float*)d_in[14];
    const float* vln1g = (const float*)d_in[15];
    const float* vln1b = (const float*)d_in[16];
    const float* vln2g = (const float*)d_in[17];
    const float* vln2b = (const float*)d_in[18];
    const float* rW   = (const float*)d_in[19];
    const float* r_as = (const float*)d_in[20];
    const float* r_ad = (const float*)d_in[21];
    const float* r_b  = (const float*)d_in[22];
    const float* rW1  = (const float*)d_in[23];
    const float* rb1  = (const float*)d_in[24];
    const float* rW2  = (const float*)d_in[25];
    const float* rb2  = (const float*)d_in[26];
    const float* rln1g = (const float*)d_in[27];
    const float* rln1b = (const float*)d_in[28];
    const float* rln2g = (const float*)d_in[29];
    const float* rln2b = (const float*)d_in[30];
    const float* We1  = (const float*)d_in[31];
    const float* be1  = (const float*)d_in[32];
    const float* We2  = (const float*)d_in[33];
    const float* be2  = (const float*)d_in[34];
    float* out = (float*)d_out;

    // workspace layout (16B-aligned segments first)
    float* X   = (float*)d_ws;                       // N*DIM
    float* Y   = X + (size_t)NODES * DIM;            // N*DIM
    unsigned short* HG = (unsigned short*)(Y + (size_t)NODES * DIM);      // N*DIM bf16
    float* ALS = (float*)(HG + (size_t)NODES * DIM); // N*HEADS
    float* ALD = ALS + (size_t)NODES * HEADS;        // N*HEADS
    __hip_bfloat16* Pb = (__hip_bfloat16*)(ALD + (size_t)NODES * HEADS);  // N*PHDIM bf16
    __hip_bfloat16* Qb = Pb + (size_t)NODES * PHDIM;                      // N*PHDIM bf16
    // per layer: W1h, W1l, W2h, W2l each 65536 bf16
    unsigned short* WT = (unsigned short*)(Qb + (size_t)NODES * PHDIM);   // 4*4*65536 bf16
    // per layer: GAT W hi/lo each 16384 bf16
    unsigned short* WXT = WT + (size_t)4 * 4 * 65536;                     // 4*2*16384 bf16
    // predictor combined weight [512][128] hi/lo
    unsigned short* WPQ = WXT + (size_t)4 * 2 * 16384;                    // 2*65536 bf16
    int* rpV = (int*)(WPQ + (size_t)2 * 65536);      // N+1
    int* ciV = rpV + (NODES + 1);                    // E
    int* rpR = ciV + NEDGE;                          // N+1
    int* ciR = rpR + (NODES + 1);                    // E
    int* cnt = ciR + NEDGE;                          // N

    const int EB = (NEDGE + 255) / 256;

    // CSR for virtual graph
    hipMemsetAsync(cnt, 0, sizeof(int) * NODES, stream);
    k_count<<<EB, 256, 0, stream>>>(eiV + NEDGE, cnt);
    k_scan<<<1, 1024, 0, stream>>>(cnt, rpV);
    hipMemsetAsync(cnt, 0, sizeof(int) * NODES, stream);
    k_fill<<<EB, 256, 0, stream>>>(eiV, rpV, cnt, ciV);
    // CSR for real graph
    hipMemsetAsync(cnt, 0, sizeof(int) * NODES, stream);
    k_count<<<EB, 256, 0, stream>>>(eiR + NEDGE, cnt);
    k_scan<<<1, 1024, 0, stream>>>(cnt, rpR);
    hipMemsetAsync(cnt, 0, sizeof(int) * NODES, stream);
    k_fill<<<EB, 256, 0, stream>>>(eiR, rpR, cnt, ciR);

    // weight transpose + split-bf16 (once per launch; L2-resident afterwards)
    for (int l = 0; l < 4; l++) {
        bool virt = (l < 2);
        int i = virt ? l : (l - 2);
        const float* W1 = (virt ? vW1 : rW1) + (size_t)i * DIM * FFDIM;
        const float* W2 = (virt ? vW2 : rW2) + (size_t)i * FFDIM * DIM;
        const float* W  = (virt ? vW : rW) + (size_t)i * DIM * DIM;
        unsigned short* base = WT + (size_t)l * 262144;
        k_wcvt2<DIM, FFDIM><<<256, 256, 0, stream>>>(W1, base, base + 65536);            // W1T[512][128] hi/lo
        k_wcvt2<FFDIM, DIM><<<256, 256, 0, stream>>>(W2, base + 131072, base + 196608);  // W2T[128][512] hi/lo
        unsigned short* bx = WXT + (size_t)l * 32768;
        k_wcvt2<DIM, DIM><<<64, 256, 0, stream>>>(W, bx, bx + 16384);                    // WT[128][128] hi/lo
    }
    k_wcvt_pq<<<256, 256, 0, stream>>>(We1, WPQ, WPQ + 65536);                           // [512][128] hi/lo

    // preprocessing
    k_preprocess<<<NODES, 128, 0, stream>>>(x0, Wp, bp, lnpg, lnpb, X);

    // 4 encoder layers: 2 virtual, 2 real
    for (int l = 0; l < 4; l++) {
        bool virt = (l < 2);
        int i = virt ? l : (l - 2);
        const float* As = (virt ? v_as : r_as) + (size_t)i * HEADS * CHC;
        const float* Ad = (virt ? v_ad : r_ad) + (size_t)i * HEADS * CHC;
        const float* Bb = (virt ? v_b : r_b) + (size_t)i * DIM;
        const float* B1 = (virt ? vb1 : rb1) + (size_t)i * FFDIM;
        const float* B2 = (virt ? vb2 : rb2) + (size_t)i * DIM;
        const float* G1 = (virt ? vln1g : rln1g) + (size_t)i * DIM;
        const float* B1n = (virt ? vln1b : rln1b) + (size_t)i * DIM;
        const float* G2 = (virt ? vln2g : rln2g) + (size_t)i * DIM;
        const float* B2n = (virt ? vln2b : rln2b) + (size_t)i * DIM;
        const int* rp = virt ? rpV : rpR;
        const int* ci = virt ? ciV : ciR;

        unsigned short* bx = WXT + (size_t)l * 32768;
        k_xw_mfma<<<(NODES + 31) / 32, 256, 0, stream>>>(X, bx, bx + 16384, As, Ad, HG, ALS, ALD);
        k_agg<<<NODES, 128, 0, stream>>>(X, HG, ALS, ALD, rp, ci, Bb, G1, B1n, Y);
        unsigned short* base = WT + (size_t)l * 262144;
        k_ffn_mfma<<<(NODES + TM - 1) / TM, 512, 0, stream>>>(
            Y, base, base + 65536, B1, base + 131072, base + 196608, B2, G2, B2n, X);
    }

    // edge predictor
    k_pq_mfma<<<(NODES + 31) / 32, 256, 0, stream>>>(X, WPQ, WPQ + 65536, be1, Pb, Qb);
    k_edge<<<(NEDGE + 3) / 4, 256, 0, stream>>>(eiR, Pb, Qb, We2, be2, out);
}

// Round 14
// 1264.899 us; speedup vs baseline: 1.4075x; 1.0847x over previous
//
#include <hip/hip_runtime.h>
#include <hip/hip_bf16.h>
#include <math.h>

#define NODES 50000
#define NFEAT 64
#define DIM 128
#define HEADS 4
#define CHC 32
#define FFDIM 512
#define PHDIM 256
#define NEDGE 600000
#define LN_EPS 1e-5f
#define SLOPE 0.2f

typedef __attribute__((ext_vector_type(8))) short bf16x8;
typedef __attribute__((ext_vector_type(4))) float f32x4;
typedef __attribute__((ext_vector_type(4))) unsigned short us4;

__device__ __forceinline__ unsigned short f2bf(float f) {
    __hip_bfloat16 h = __float2bfloat16(f);
    return reinterpret_cast<unsigned short&>(h);
}
__device__ __forceinline__ float bf2f(unsigned short u) {
    return __uint_as_float(((unsigned int)u) << 16);
}

// ---------- helpers ----------
__device__ __forceinline__ void ln_stats128(float val, float* red, float& mean, float& rstd) {
    float s1 = val, s2 = val * val;
#pragma unroll
    for (int off = 32; off > 0; off >>= 1) {
        s1 += __shfl_xor(s1, off, 64);
        s2 += __shfl_xor(s2, off, 64);
    }
    int wv = threadIdx.x >> 6;
    if ((threadIdx.x & 63) == 0) { red[wv * 2] = s1; red[wv * 2 + 1] = s2; }
    __syncthreads();
    float t1 = red[0] + red[2];
    float t2 = red[1] + red[3];
    mean = t1 * (1.f / 128.f);
    float var = t2 * (1.f / 128.f) - mean * mean;
    rstd = rsqrtf(var + LN_EPS);
}

// ---------- CSR build (both graphs per launch) ----------
__global__ void k_count2(const int* __restrict__ dstV, const int* __restrict__ dstR,
                         int* __restrict__ cntV, int* __restrict__ cntR) {
    int e = blockIdx.x * 256 + threadIdx.x;
    if (e < NEDGE) atomicAdd(&cntV[dstV[e]], 1);
    else if (e < 2 * NEDGE) atomicAdd(&cntR[dstR[e - NEDGE]], 1);
}

__global__ void k_scan2(const int* __restrict__ degV, int* __restrict__ rpV,
                        const int* __restrict__ degR, int* __restrict__ rpR) {
    __shared__ int sh[1024];
    const int* deg = blockIdx.x ? degR : degV;
    int* rp = blockIdx.x ? rpR : rpV;
    int t = threadIdx.x;
    const int per = (NODES + 1023) / 1024;
    int beg = t * per;
    int end = beg + per; if (end > NODES) end = NODES; if (beg > NODES) beg = NODES;
    int s = 0;
    for (int i = beg; i < end; i++) s += deg[i];
    sh[t] = s;
    __syncthreads();
    for (int off = 1; off < 1024; off <<= 1) {
        int v = (t >= off) ? sh[t - off] : 0;
        __syncthreads();
        sh[t] += v;
        __syncthreads();
    }
    int run = sh[t] - s;  // exclusive prefix
    for (int i = beg; i < end; i++) { rp[i] = run; run += deg[i]; }
    if (t == 1023) rp[NODES] = sh[1023];
}

__global__ void k_fill2(const int* __restrict__ eiV, const int* __restrict__ eiR,
                        const int* __restrict__ rpV, const int* __restrict__ rpR,
                        int* __restrict__ cntV, int* __restrict__ cntR,
                        int* __restrict__ ciV, int* __restrict__ ciR) {
    int e = blockIdx.x * 256 + threadIdx.x;
    if (e < NEDGE) {
        int s = eiV[e], d = eiV[NEDGE + e];
        int pos = atomicAdd(&cntV[d], 1);
        ciV[rpV[d] + pos] = s;
    } else if (e < 2 * NEDGE) {
        int e2 = e - NEDGE;
        int s = eiR[e2], d = eiR[NEDGE + e2];
        int pos = atomicAdd(&cntR[d], 1);
        ciR[rpR[d] + pos] = s;
    }
}

// ---------- weight transpose + split-bf16, batched over 4 layers (blockIdx.y) ----------
// out[n*KI+k] = bf16 hi/lo of in[k*NR+n]; layer l<2 from inV[l], else inR[l-2].
template <int KI, int NR>
__global__ void k_wcvt2b(const float* __restrict__ inV, const float* __restrict__ inR,
                         unsigned short* __restrict__ oh, unsigned short* __restrict__ ol,
                         size_t ostride) {
    int l = blockIdx.y;
    const float* in = (l < 2 ? inV : inR) + (size_t)(l & 1) * KI * NR;
    unsigned short* ohp = oh + (size_t)l * ostride;
    unsigned short* olp = ol + (size_t)l * ostride;
    int tid = blockIdx.x * 256 + threadIdx.x;  // KI*NR total
    int n = tid / KI, k = tid % KI;
    float w = in[k * NR + n];
    unsigned short h = f2bf(w);
    ohp[tid] = h;
    olp[tid] = f2bf(w - bf2f(h));
}

// We1 [2*DIM][PHDIM] -> combined [512][128] hi/lo: rows 0-255 = P cols (We1 top),
// rows 256-511 = Q cols (We1 bottom)
__global__ void k_wcvt_pq(const float* __restrict__ We1, unsigned short* __restrict__ oh,
                          unsigned short* __restrict__ ol) {
    int tid = blockIdx.x * 256 + threadIdx.x;  // 512*128
    int n = tid >> 7, k = tid & 127;
    float w = (n < PHDIM) ? We1[k * PHDIM + n] : We1[(DIM + k) * PHDIM + (n - PHDIM)];
    unsigned short h = f2bf(w);
    oh[tid] = h;
    ol[tid] = f2bf(w - bf2f(h));
}

// ---------- preprocessing: x = LN(relu(x0 @ Wp + bp)) ----------
__global__ void k_preprocess(const float* __restrict__ x0, const float* __restrict__ Wp,
                             const float* __restrict__ bp, const float* __restrict__ g,
                             const float* __restrict__ b, float* __restrict__ xout) {
    __shared__ float xr[NFEAT];
    __shared__ float red[4];
    int n = blockIdx.x;
    int j = threadIdx.x;
    if (j < NFEAT) xr[j] = x0[n * NFEAT + j];
    __syncthreads();
    float acc = bp[j];
#pragma unroll
    for (int k = 0; k < NFEAT; k++) acc += xr[k] * Wp[k * DIM + j];
    acc = fmaxf(acc, 0.f);
    float mean, rstd;
    ln_stats128(acc, red, mean, rstd);
    xout[n * DIM + j] = (acc - mean) * rstd * g[j] + b[j];
}

#define XS_STRIDE 136   // 128 + 8 bf16 pad (272 B rows, 16B-aligned)
#define HID_STRIDE 520  // 512 + 8 bf16 pad (1040 B rows)
#define FB_STRIDE 132   // fp32 resid buffer stride
#define MFMA_BF16 __builtin_amdgcn_mfma_f32_16x16x32_bf16

// ---------- split-bf16 MFMA: hg = x @ W (bf16 out) ; fused attention logits ----------
// NO __launch_bounds__ on split-bf16 MFMA kernels (session finding).
__global__ void k_xw_mfma(const float* __restrict__ x,
                          const unsigned short* __restrict__ Wh,
                          const unsigned short* __restrict__ Wl,
                          const float* __restrict__ a_s, const float* __restrict__ a_d,
                          unsigned short* __restrict__ hg, float* __restrict__ als,
                          float* __restrict__ ald) {
    __shared__ __align__(16) unsigned short xsh[32 * XS_STRIDE];
    __shared__ __align__(16) unsigned short xsl[32 * XS_STRIDE];
    int t = threadIdx.x;
    int n0 = blockIdx.x * 32;

#pragma unroll
    for (int jj = 0; jj < 4; jj++) {
        int v = t + jj * 256;  // 1024 float4s = 32 rows x 32 float4
        int m = v >> 5, c4 = (v & 31) * 4;
        int node = n0 + m;
        float4 f;
        if (node < NODES) f = *(const float4*)(x + (size_t)node * DIM + c4);
        else { f.x = f.y = f.z = f.w = 0.f; }
        us4 uh = {f2bf(f.x), f2bf(f.y), f2bf(f.z), f2bf(f.w)};
        us4 ul = {f2bf(f.x - bf2f(uh.x)), f2bf(f.y - bf2f(uh.y)),
                  f2bf(f.z - bf2f(uh.z)), f2bf(f.w - bf2f(uh.w))};
        *(us4*)(xsh + m * XS_STRIDE + c4) = uh;
        *(us4*)(xsl + m * XS_STRIDE + c4) = ul;
    }
    __syncthreads();

    int wv = t >> 6, l = t & 63, lr = l & 15, lk = l >> 4;

    f32x4 acc[2][2];
#pragma unroll
    for (int mf = 0; mf < 2; mf++)
#pragma unroll
        for (int nf = 0; nf < 2; nf++) acc[mf][nf] = (f32x4){0.f, 0.f, 0.f, 0.f};
#pragma unroll
    for (int kk = 0; kk < 4; kk++) {
        int c = kk * 32 + lk * 8;
        bf16x8 a0h = *(const bf16x8*)(xsh + lr * XS_STRIDE + c);
        bf16x8 a0l = *(const bf16x8*)(xsl + lr * XS_STRIDE + c);
        bf16x8 a1h = *(const bf16x8*)(xsh + (16 + lr) * XS_STRIDE + c);
        bf16x8 a1l = *(const bf16x8*)(xsl + (16 + lr) * XS_STRIDE + c);
#pragma unroll
        for (int nf = 0; nf < 2; nf++) {
            int n = wv * 32 + nf * 16 + lr;
            bf16x8 bh = *(const bf16x8*)(Wh + (size_t)n * DIM + c);
            bf16x8 bl = *(const bf16x8*)(Wl + (size_t)n * DIM + c);
            acc[0][nf] = MFMA_BF16(a0h, bh, acc[0][nf], 0, 0, 0);
            acc[0][nf] = MFMA_BF16(a0l, bh, acc[0][nf], 0, 0, 0);
            acc[0][nf] = MFMA_BF16(a0h, bl, acc[0][nf], 0, 0, 0);
            acc[1][nf] = MFMA_BF16(a1h, bh, acc[1][nf], 0, 0, 0);
            acc[1][nf] = MFMA_BF16(a1l, bh, acc[1][nf], 0, 0, 0);
            acc[1][nf] = MFMA_BF16(a1h, bl, acc[1][nf], 0, 0, 0);
        }
    }

    float as0 = a_s[wv * 32 + lr], as1 = a_s[wv * 32 + 16 + lr];
    float ad0 = a_d[wv * 32 + lr], ad1 = a_d[wv * 32 + 16 + lr];
#pragma unroll
    for (int mf = 0; mf < 2; mf++) {
#pragma unroll
        for (int r = 0; r < 4; r++) {
            int m = mf * 16 + lk * 4 + r;
            int node = n0 + m;
            float v0 = acc[mf][0][r], v1 = acc[mf][1][r];
            if (node < NODES) {
                hg[(size_t)node * DIM + wv * 32 + lr] = f2bf(v0);
                hg[(size_t)node * DIM + wv * 32 + 16 + lr] = f2bf(v1);
            }
            float ps = v0 * as0 + v1 * as1;
            float pd = v0 * ad0 + v1 * ad1;
#pragma unroll
            for (int off = 8; off > 0; off >>= 1) {
                ps += __shfl_xor(ps, off, 64);
                pd += __shfl_xor(pd, off, 64);
            }
            if (lr == 0 && node < NODES) {
                als[node * HEADS + wv] = ps;
                ald[node * HEADS + wv] = pd;
            }
        }
    }
}

// ---------- GAT aggregate + bias + residual + LN (4-deep edge pipeline, bf16 hg) ----------
__global__ void k_agg(const float* __restrict__ x, const unsigned short* __restrict__ hg,
                      const float* __restrict__ als, const float* __restrict__ ald,
                      const int* __restrict__ rp, const int* __restrict__ ci,
                      const float* __restrict__ bias, const float* __restrict__ g,
                      const float* __restrict__ b, float* __restrict__ y) {
    __shared__ float red[4];
    int n = blockIdx.x, j = threadIdx.x, head = j >> 5;
    float aldn = ald[n * HEADS + head];
    float a0 = als[n * HEADS + head] + aldn;
    a0 = (a0 > 0.f) ? a0 : SLOPE * a0;
    float ex = __expf(a0);
    float den = ex;
    float acc = ex * bf2f(hg[(size_t)n * DIM + j]);
    int beg = rp[n], end = rp[n + 1];
    int e = beg;
    for (; e + 4 <= end; e += 4) {
        int s0 = ci[e], s1 = ci[e + 1], s2 = ci[e + 2], s3 = ci[e + 3];
        float av0 = als[s0 * HEADS + head] + aldn;
        float av1 = als[s1 * HEADS + head] + aldn;
        float av2 = als[s2 * HEADS + head] + aldn;
        float av3 = als[s3 * HEADS + head] + aldn;
        av0 = (av0 > 0.f) ? av0 : SLOPE * av0;
        av1 = (av1 > 0.f) ? av1 : SLOPE * av1;
        av2 = (av2 > 0.f) ? av2 : SLOPE * av2;
        av3 = (av3 > 0.f) ? av3 : SLOPE * av3;
        float e0 = __expf(av0), e1 = __expf(av1), e2 = __expf(av2), e3 = __expf(av3);
        float h0 = bf2f(hg[(size_t)s0 * DIM + j]);
        float h1 = bf2f(hg[(size_t)s1 * DIM + j]);
        float h2 = bf2f(hg[(size_t)s2 * DIM + j]);
        float h3 = bf2f(hg[(size_t)s3 * DIM + j]);
        den += (e0 + e1) + (e2 + e3);
        acc += e0 * h0 + e1 * h1 + e2 * h2 + e3 * h3;
    }
    for (; e < end; e++) {
        int s = ci[e];
        float av = als[s * HEADS + head] + aldn;
        av = (av > 0.f) ? av : SLOPE * av;
        float e2 = __expf(av);
        den += e2;
        acc += e2 * bf2f(hg[(size_t)s * DIM + j]);
    }
    float val = x[(size_t)n * DIM + j] + acc / den + bias[j];
    float mean, rstd;
    ln_stats128(val, red, mean, rstd);
    y[(size_t)n * DIM + j] = (val - mean) * rstd * g[j] + b[j];
}

// ---------- split-bf16 MFMA fused FFN: x = LN(y + relu(y@W1+b1)@W2+b2) ----------
// R8/R10 512-thread version, EXACT (passing, frozen). Session laws: only
// correct at 1 block/CU (84KB LDS); 512 threads is the throughput optimum
// (1024-thread re-wave halved MfmaUtil — R11). Do not modify.
#define TM 32

__global__ void k_ffn_mfma(
    const float* __restrict__ yin,
    const unsigned short* __restrict__ W1h, const unsigned short* __restrict__ W1l,
    const float* __restrict__ b1,
    const unsigned short* __restrict__ W2h, const unsigned short* __restrict__ W2l,
    const float* __restrict__ b2, const float* __restrict__ g,
    const float* __restrict__ b, float* __restrict__ xout) {
    __shared__ __align__(16) unsigned char smem[(2 * TM * XS_STRIDE + 2 * TM * HID_STRIDE) * 2];
    unsigned short* xsh = (unsigned short*)smem;        // [32][136] bf16 hi
    unsigned short* xsl = xsh + TM * XS_STRIDE;         // [32][136] bf16 lo
    unsigned short* hidh = xsl + TM * XS_STRIDE;        // [32][520] bf16 hi
    unsigned short* hidl = hidh + TM * HID_STRIDE;      // [32][520] bf16 lo
    float* fbuf = (float*)hidh;                         // reuse: [32][132] fp32

    int t = threadIdx.x;  // 512
    int n0 = blockIdx.x * TM;

    // stage yin tile -> split bf16 LDS (1024 float4s = 32 rows x 32 float4)
#pragma unroll
    for (int jj = 0; jj < 2; jj++) {
        int v = t + jj * 512;
        int m = v >> 5, c4 = (v & 31) * 4;
        int node = n0 + m;
        float4 f;
        if (node < NODES) f = *(const float4*)(yin + (size_t)node * DIM + c4);
        else { f.x = f.y = f.z = f.w = 0.f; }
        us4 uh = {f2bf(f.x), f2bf(f.y), f2bf(f.z), f2bf(f.w)};
        us4 ul = {f2bf(f.x - bf2f(uh.x)), f2bf(f.y - bf2f(uh.y)),
                  f2bf(f.z - bf2f(uh.z)), f2bf(f.w - bf2f(uh.w))};
        *(us4*)(xsh + m * XS_STRIDE + c4) = uh;
        *(us4*)(xsl + m * XS_STRIDE + c4) = ul;
    }
    __syncthreads();

    int wv = t >> 6, l = t & 63, lr = l & 15, lk = l >> 4;  // wv in [0,8)

    // phase 1: hid = relu(xs @ W1 + b1); wave wv owns hidden cols [wv*64, wv*64+64)
    {
        f32x4 acc[2][4];
#pragma unroll
        for (int mf = 0; mf < 2; mf++)
#pragma unroll
            for (int nf = 0; nf < 4; nf++) acc[mf][nf] = (f32x4){0.f, 0.f, 0.f, 0.f};
#pragma unroll
        for (int kk = 0; kk < 4; kk++) {
            int c = kk * 32 + lk * 8;
            bf16x8 a0h = *(const bf16x8*)(xsh + lr * XS_STRIDE + c);
            bf16x8 a0l = *(const bf16x8*)(xsl + lr * XS_STRIDE + c);
            bf16x8 a1h = *(const bf16x8*)(xsh + (16 + lr) * XS_STRIDE + c);
            bf16x8 a1l = *(const bf16x8*)(xsl + (16 + lr) * XS_STRIDE + c);
#pragma unroll
            for (int nf = 0; nf < 4; nf++) {
                int n = wv * 64 + nf * 16 + lr;
                bf16x8 bh = *(const bf16x8*)(W1h + (size_t)n * DIM + c);
                bf16x8 bl = *(const bf16x8*)(W1l + (size_t)n * DIM + c);
                acc[0][nf] = MFMA_BF16(a0h, bh, acc[0][nf], 0, 0, 0);
                acc[0][nf] = MFMA_BF16(a0l, bh, acc[0][nf], 0, 0, 0);
                acc[0][nf] = MFMA_BF16(a0h, bl, acc[0][nf], 0, 0, 0);
                acc[1][nf] = MFMA_BF16(a1h, bh, acc[1][nf], 0, 0, 0);
                acc[1][nf] = MFMA_BF16(a1l, bh, acc[1][nf], 0, 0, 0);
                acc[1][nf] = MFMA_BF16(a1h, bl, acc[1][nf], 0, 0, 0);
            }
        }
#pragma unroll
        for (int nf = 0; nf < 4; nf++) {
            int n = wv * 64 + nf * 16 + lr;
            float bias = b1[n];
#pragma unroll
            for (int mf = 0; mf < 2; mf++)
#pragma unroll
                for (int r = 0; r < 4; r++) {
                    int m = mf * 16 + lk * 4 + r;
                    float val = fmaxf(acc[mf][nf][r] + bias, 0.f);
                    unsigned short h = f2bf(val);
                    hidh[m * HID_STRIDE + n] = h;
                    hidl[m * HID_STRIDE + n] = f2bf(val - bf2f(h));
                }
        }
    }
    __syncthreads();

    // phase 2: f = hid @ W2; wave wv owns out cols [wv*16, wv*16+16)
    f32x4 acc2[2];
#pragma unroll
    for (int mf = 0; mf < 2; mf++) acc2[mf] = (f32x4){0.f, 0.f, 0.f, 0.f};
#pragma unroll
    for (int kk = 0; kk < 16; kk++) {
        int c = kk * 32 + lk * 8;
        bf16x8 a0h = *(const bf16x8*)(hidh + lr * HID_STRIDE + c);
        bf16x8 a0l = *(const bf16x8*)(hidl + lr * HID_STRIDE + c);
        bf16x8 a1h = *(const bf16x8*)(hidh + (16 + lr) * HID_STRIDE + c);
        bf16x8 a1l = *(const bf16x8*)(hidl + (16 + lr) * HID_STRIDE + c);
        int n = wv * 16 + lr;
        bf16x8 bh = *(const bf16x8*)(W2h + (size_t)n * FFDIM + c);
        bf16x8 bl = *(const bf16x8*)(W2l + (size_t)n * FFDIM + c);
        acc2[0] = MFMA_BF16(a0h, bh, acc2[0], 0, 0, 0);
        acc2[0] = MFMA_BF16(a0l, bh, acc2[0], 0, 0, 0);
        acc2[0] = MFMA_BF16(a0h, bl, acc2[0], 0, 0, 0);
        acc2[1] = MFMA_BF16(a1h, bh, acc2[1], 0, 0, 0);
        acc2[1] = MFMA_BF16(a1l, bh, acc2[1], 0, 0, 0);
        acc2[1] = MFMA_BF16(a1h, bl, acc2[1], 0, 0, 0);
    }
    __syncthreads();  // all hid reads done before fbuf overwrite

    // residual + bias into fp32 LDS
    {
        int n = wv * 16 + lr;
        float bias = b2[n];
#pragma unroll
        for (int mf = 0; mf < 2; mf++)
#pragma unroll
            for (int r = 0; r < 4; r++) {
                int m = mf * 16 + lk * 4 + r;
                int node = n0 + m;
                float yv = (node < NODES) ? yin[(size_t)node * DIM + n] : 0.f;
                fbuf[m * FB_STRIDE + n] = acc2[mf][r] + bias + yv;
            }
    }
    __syncthreads();

    // LN: 16 threads per row, 8 cols each (512 threads / 32 rows)
    {
        int row = t >> 4, l16 = t & 15;
        float4 vv[2];
        float s1 = 0.f, s2 = 0.f;
#pragma unroll
        for (int q = 0; q < 2; q++) {
            vv[q] = *(float4*)(fbuf + row * FB_STRIDE + l16 * 8 + q * 4);
            s1 += vv[q].x + vv[q].y + vv[q].z + vv[q].w;
            s2 += vv[q].x * vv[q].x + vv[q].y * vv[q].y + vv[q].z * vv[q].z + vv[q].w * vv[q].w;
        }
#pragma unroll
        for (int off = 8; off > 0; off >>= 1) {
            s1 += __shfl_xor(s1, off, 64);
            s2 += __shfl_xor(s2, off, 64);
        }
        float mean = s1 * (1.f / 128.f);
        float var = s2 * (1.f / 128.f) - mean * mean;
        float rstd = rsqrtf(var + LN_EPS);
        int node = n0 + row;
        if (node < NODES) {
#pragma unroll
            for (int q = 0; q < 2; q++) {
                int c = l16 * 8 + q * 4;
                float4 gv = *(const float4*)(g + c);
                float4 bv = *(const float4*)(b + c);
                float4 o;
                o.x = (vv[q].x - mean) * rstd * gv.x + bv.x;
                o.y = (vv[q].y - mean) * rstd * gv.y + bv.y;
                o.z = (vv[q].z - mean) * rstd * gv.z + bv.z;
                o.w = (vv[q].w - mean) * rstd * gv.w + bv.w;
                *(float4*)(xout + (size_t)node * DIM + c) = o;
            }
        }
    }
}

// ---------- split-bf16 MFMA predictor precompute: P,Q (bf16) ----------
__global__ void k_pq_mfma(const float* __restrict__ x,
                          const unsigned short* __restrict__ Wh,
                          const unsigned short* __restrict__ Wl,
                          const float* __restrict__ be1,
                          __hip_bfloat16* __restrict__ P, __hip_bfloat16* __restrict__ Q) {
    __shared__ __align__(16) unsigned short xsh[32 * XS_STRIDE];
    __shared__ __align__(16) unsigned short xsl[32 * XS_STRIDE];
    int t = threadIdx.x;
    int n0 = blockIdx.x * 32;

#pragma unroll
    for (int jj = 0; jj < 4; jj++) {
        int v = t + jj * 256;
        int m = v >> 5, c4 = (v & 31) * 4;
        int node = n0 + m;
        float4 f;
        if (node < NODES) f = *(const float4*)(x + (size_t)node * DIM + c4);
        else { f.x = f.y = f.z = f.w = 0.f; }
        us4 uh = {f2bf(f.x), f2bf(f.y), f2bf(f.z), f2bf(f.w)};
        us4 ul = {f2bf(f.x - bf2f(uh.x)), f2bf(f.y - bf2f(uh.y)),
                  f2bf(f.z - bf2f(uh.z)), f2bf(f.w - bf2f(uh.w))};
        *(us4*)(xsh + m * XS_STRIDE + c4) = uh;
        *(us4*)(xsl + m * XS_STRIDE + c4) = ul;
    }
    __syncthreads();

    int wv = t >> 6, l = t & 63, lr = l & 15, lk = l >> 4;

    f32x4 acc[2][8];
#pragma unroll
    for (int mf = 0; mf < 2; mf++)
#pragma unroll
        for (int nf = 0; nf < 8; nf++) acc[mf][nf] = (f32x4){0.f, 0.f, 0.f, 0.f};
#pragma unroll
    for (int kk = 0; kk < 4; kk++) {
        int c = kk * 32 + lk * 8;
        bf16x8 a0h = *(const bf16x8*)(xsh + lr * XS_STRIDE + c);
        bf16x8 a0l = *(const bf16x8*)(xsl + lr * XS_STRIDE + c);
        bf16x8 a1h = *(const bf16x8*)(xsh + (16 + lr) * XS_STRIDE + c);
        bf16x8 a1l = *(const bf16x8*)(xsl + (16 + lr) * XS_STRIDE + c);
#pragma unroll
        for (int nf = 0; nf < 8; nf++) {
            int n = wv * 128 + nf * 16 + lr;
            bf16x8 bh = *(const bf16x8*)(Wh + (size_t)n * DIM + c);
            bf16x8 bl = *(const bf16x8*)(Wl + (size_t)n * DIM + c);
            acc[0][nf] = MFMA_BF16(a0h, bh, acc[0][nf], 0, 0, 0);
            acc[0][nf] = MFMA_BF16(a0l, bh, acc[0][nf], 0, 0, 0);
            acc[0][nf] = MFMA_BF16(a0h, bl, acc[0][nf], 0, 0, 0);
            acc[1][nf] = MFMA_BF16(a1h, bh, acc[1][nf], 0, 0, 0);
            acc[1][nf] = MFMA_BF16(a1l, bh, acc[1][nf], 0, 0, 0);
            acc[1][nf] = MFMA_BF16(a1h, bl, acc[1][nf], 0, 0, 0);
        }
    }

#pragma unroll
    for (int nf = 0; nf < 8; nf++) {
        int n = wv * 128 + nf * 16 + lr;     // [0,512)
        float bias = (n < PHDIM) ? be1[n] : 0.f;
        __hip_bfloat16* dst = (n < PHDIM) ? P : Q;   // wave-uniform
        int col = n & (PHDIM - 1);
#pragma unroll
        for (int mf = 0; mf < 2; mf++)
#pragma unroll
            for (int r = 0; r < 4; r++) {
                int m = mf * 16 + lk * 4 + r;
                int node = n0 + m;
                if (node < NODES)
                    dst[(size_t)node * PHDIM + col] = __float2bfloat16(acc[mf][nf][r] + bias);
            }
    }
}

// ---------- edge predictor: flow = relu(relu(P[s]+Q[d]) . We2 + be2) ----------
// 512 threads / 8 edges per block (fewer blocks, same per-edge math).
__global__ void k_edge(const int* __restrict__ ei, const __hip_bfloat16* __restrict__ P,
                       const __hip_bfloat16* __restrict__ Q, const float* __restrict__ We2,
                       const float* __restrict__ be2, float* __restrict__ out) {
    int lane = threadIdx.x & 63;
    int wv = threadIdx.x >> 6;
    int e = blockIdx.x * 8 + wv;
    if (e >= NEDGE) return;
    float4 w2 = ((const float4*)We2)[lane];
    int s = ei[e], d = ei[NEDGE + e];
    uint2 pu = ((const uint2*)P)[(size_t)s * 64 + lane];
    uint2 qu = ((const uint2*)Q)[(size_t)d * 64 + lane];
    float p0 = __uint_as_float(pu.x << 16);
    float p1 = __uint_as_float(pu.x & 0xffff0000u);
    float p2 = __uint_as_float(pu.y << 16);
    float p3 = __uint_as_float(pu.y & 0xffff0000u);
    float q0 = __uint_as_float(qu.x << 16);
    float q1 = __uint_as_float(qu.x & 0xffff0000u);
    float q2 = __uint_as_float(qu.y << 16);
    float q3 = __uint_as_float(qu.y & 0xffff0000u);
    float acc = fmaxf(p0 + q0, 0.f) * w2.x + fmaxf(p1 + q1, 0.f) * w2.y +
                fmaxf(p2 + q2, 0.f) * w2.z + fmaxf(p3 + q3, 0.f) * w2.w;
#pragma unroll
    for (int off = 32; off > 0; off >>= 1) acc += __shfl_xor(acc, off, 64);
    if (lane == 0) out[e] = fmaxf(acc + be2[0], 0.f);
}

extern "C" void kernel_launch(void* const* d_in, const int* in_sizes, int n_in,
                              void* d_out, int out_size, void* d_ws, size_t ws_size,
                              hipStream_t stream) {
    const float* x0   = (const float*)d_in[0];
    const int*   eiR  = (const int*)d_in[1];
    const int*   eiV  = (const int*)d_in[2];
    const float* Wp   = (const float*)d_in[3];
    const float* bp   = (const float*)d_in[4];
    const float* lnpg = (const float*)d_in[5];
    const float* lnpb = (const float*)d_in[6];
    const float* vW   = (const float*)d_in[7];
    const float* v_as = (const float*)d_in[8];
    const float* v_ad = (const float*)d_in[9];
    const float* v_b  = (const float*)d_in[10];
    const float* vW1  = (const float*)d_in[11];
    const float* vb1  = (const float*)d_in[12];
    const float* vW2  = (const float*)d_in[13];
    const float* vb2  = (const float*)d_in[14];
    const float* vln1g = (const float*)d_in[15];
    const float* vln1b = (const float*)d_in[16];
    const float* vln2g = (const float*)d_in[17];
    const float* vln2b = (const float*)d_in[18];
    const float* rW   = (const float*)d_in[19];
    const float* r_as = (const float*)d_in[20];
    const float* r_ad = (const float*)d_in[21];
    const float* r_b  = (const float*)d_in[22];
    const float* rW1  = (const float*)d_in[23];
    const float* rb1  = (const float*)d_in[24];
    const float* rW2  = (const float*)d_in[25];
    const float* rb2  = (const float*)d_in[26];
    const float* rln1g = (const float*)d_in[27];
    const float* rln1b = (const float*)d_in[28];
    const float* rln2g = (const float*)d_in[29];
    const float* rln2b = (const float*)d_in[30];
    const float* We1  = (const float*)d_in[31];
    const float* be1  = (const float*)d_in[32];
    const float* We2  = (const float*)d_in[33];
    const float* be2  = (const float*)d_in[34];
    float* out = (float*)d_out;

    // workspace layout (16B-aligned segments first)
    float* X   = (float*)d_ws;                       // N*DIM
    float* Y   = X + (size_t)NODES * DIM;            // N*DIM
    unsigned short* HG = (unsigned short*)(Y + (size_t)NODES * DIM);      // N*DIM bf16
    float* ALS = (float*)(HG + (size_t)NODES * DIM); // N*HEADS
    float* ALD = ALS + (size_t)NODES * HEADS;        // N*HEADS
    __hip_bfloat16* Pb = (__hip_bfloat16*)(ALD + (size_t)NODES * HEADS);  // N*PHDIM bf16
    __hip_bfloat16* Qb = Pb + (size_t)NODES * PHDIM;                      // N*PHDIM bf16
    // per layer: W1h, W1l, W2h, W2l each 65536 bf16
    unsigned short* WT = (unsigned short*)(Qb + (size_t)NODES * PHDIM);   // 4*4*65536 bf16
    // per layer: GAT W hi/lo each 16384 bf16
    unsigned short* WXT = WT + (size_t)4 * 4 * 65536;                     // 4*2*16384 bf16
    // predictor combined weight [512][128] hi/lo
    unsigned short* WPQ = WXT + (size_t)4 * 2 * 16384;                    // 2*65536 bf16
    int* rpV = (int*)(WPQ + (size_t)2 * 65536);      // N+1
    int* ciV = rpV + (NODES + 1);                    // E
    int* rpR = ciV + NEDGE;                          // N+1
    int* ciR = rpR + (NODES + 1);                    // E
    int* cntV = ciR + NEDGE;                         // N
    int* cntR = cntV + NODES;                        // N

    const int EB2 = (2 * NEDGE + 255) / 256;

    // CSR for both graphs (merged launches)
    hipMemsetAsync(cntV, 0, sizeof(int) * 2 * NODES, stream);
    k_count2<<<EB2, 256, 0, stream>>>(eiV + NEDGE, eiR + NEDGE, cntV, cntR);
    k_scan2<<<2, 1024, 0, stream>>>(cntV, rpV, cntR, rpR);
    hipMemsetAsync(cntV, 0, sizeof(int) * 2 * NODES, stream);
    k_fill2<<<EB2, 256, 0, stream>>>(eiV, eiR, rpV, rpR, cntV, cntR, ciV, ciR);

    // weight transpose + split-bf16, batched over layers (once per launch)
    {
        dim3 g1(256, 4);  // W1: 65536 elems/layer
        k_wcvt2b<DIM, FFDIM><<<g1, 256, 0, stream>>>(vW1, rW1, WT, WT + 65536, 262144);
        dim3 g2(256, 4);  // W2
        k_wcvt2b<FFDIM, DIM><<<g2, 256, 0, stream>>>(vW2, rW2, WT + 131072, WT + 196608, 262144);
        dim3 g3(64, 4);   // GAT W: 16384 elems/layer
        k_wcvt2b<DIM, DIM><<<g3, 256, 0, stream>>>(vW, rW, WXT, WXT + 16384, 32768);
        k_wcvt_pq<<<256, 256, 0, stream>>>(We1, WPQ, WPQ + 65536);
    }

    // preprocessing
    k_preprocess<<<NODES, 128, 0, stream>>>(x0, Wp, bp, lnpg, lnpb, X);

    // 4 encoder layers: 2 virtual, 2 real
    for (int l = 0; l < 4; l++) {
        bool virt = (l < 2);
        int i = virt ? l : (l - 2);
        const float* As = (virt ? v_as : r_as) + (size_t)i * HEADS * CHC;
        const float* Ad = (virt ? v_ad : r_ad) + (size_t)i * HEADS * CHC;
        const float* Bb = (virt ? v_b : r_b) + (size_t)i * DIM;
        const float* B1 = (virt ? vb1 : rb1) + (size_t)i * FFDIM;
        const float* B2 = (virt ? vb2 : rb2) + (size_t)i * DIM;
        const float* G1 = (virt ? vln1g : rln1g) + (size_t)i * DIM;
        const float* B1n = (virt ? vln1b : rln1b) + (size_t)i * DIM;
        const float* G2 = (virt ? vln2g : rln2g) + (size_t)i * DIM;
        const float* B2n = (virt ? vln2b : rln2b) + (size_t)i * DIM;
        const int* rp = virt ? rpV : rpR;
        const int* ci = virt ? ciV : ciR;

        unsigned short* bx = WXT + (size_t)l * 32768;
        k_xw_mfma<<<(NODES + 31) / 32, 256, 0, stream>>>(X, bx, bx + 16384, As, Ad, HG, ALS, ALD);
        k_agg<<<NODES, 128, 0, stream>>>(X, HG, ALS, ALD, rp, ci, Bb, G1, B1n, Y);
        unsigned short* base = WT + (size_t)l * 262144;
        k_ffn_mfma<<<(NODES + TM - 1) / TM, 512, 0, stream>>>(
            Y, base, base + 65536, B1, base + 131072, base + 196608, B2, G2, B2n, X);
    }

    // edge predictor
    k_pq_mfma<<<(NODES + 31) / 32, 256, 0, stream>>>(X, WPQ, WPQ + 65536, be1, Pb, Qb);
    k_edge<<<(NEDGE + 7) / 8, 512, 0, stream>>>(eiR, Pb, Qb, We2, be2, out);
}